// Round 9
// baseline (2816.590 us; speedup 1.0000x reference)
//
#include <hip/hip_runtime.h>
#include <hip/hip_bf16.h>
#include <float.h>

#define NPTS    4096
#define NPOINT  1024
#define NSAMPLE 32
#define BATCH   16
#define NTOT    (BATCH * NPOINT * NSAMPLE)   // 524288 gathered pairs
#define INV_NTOT (1.0f / 524288.0f)
#define BN_EPS  1e-5f

// ---------------------------------------------------------------------------
// DPP wave-64 reduction helpers (pure VALU — no LDS-pipe bpermute/swizzle).
// ---------------------------------------------------------------------------
template<int CTRL, int OLD>
__device__ __forceinline__ unsigned long long dpp_move_u64(unsigned long long v) {
    const int lo = __builtin_amdgcn_update_dpp(OLD, (int)(unsigned)v,        CTRL, 0xF, 0xF, false);
    const int hi = __builtin_amdgcn_update_dpp(OLD, (int)(unsigned)(v >> 32), CTRL, 0xF, 0xF, false);
    return ((unsigned long long)(unsigned)hi << 32) | (unsigned)lo;
}

__device__ __forceinline__ unsigned long long dpp_max64_to_lane63(unsigned long long v) {
    unsigned long long o;
    o = dpp_move_u64<0x111, 0>(v); v = o > v ? o : v;
    o = dpp_move_u64<0x112, 0>(v); v = o > v ? o : v;
    o = dpp_move_u64<0x114, 0>(v); v = o > v ? o : v;
    o = dpp_move_u64<0x118, 0>(v); v = o > v ? o : v;
    o = dpp_move_u64<0x142, 0>(v); v = o > v ? o : v;
    o = dpp_move_u64<0x143, 0>(v); v = o > v ? o : v;
    return v;
}

__device__ __forceinline__ unsigned long long dpp_min64_to_lane63(unsigned long long v) {
    unsigned long long o;
    o = dpp_move_u64<0x111, -1>(v); v = o < v ? o : v;
    o = dpp_move_u64<0x112, -1>(v); v = o < v ? o : v;
    o = dpp_move_u64<0x114, -1>(v); v = o < v ? o : v;
    o = dpp_move_u64<0x118, -1>(v); v = o < v ? o : v;
    o = dpp_move_u64<0x142, -1>(v); v = o < v ? o : v;
    o = dpp_move_u64<0x143, -1>(v); v = o < v ? o : v;
    return v;
}

__device__ __forceinline__ unsigned long long readlane63_u64(unsigned long long v) {
    const unsigned lo = (unsigned)__builtin_amdgcn_readlane((int)(unsigned)v, 63);
    const unsigned hi = (unsigned)__builtin_amdgcn_readlane((int)(unsigned)(v >> 32), 63);
    return ((unsigned long long)hi << 32) | lo;
}

// ---------------------------------------------------------------------------
__global__ void init_stats_kernel(float* __restrict__ stats) {
    stats[threadIdx.x] = 0.0f;
}

// ---------------------------------------------------------------------------
// K1: FPS, batch-pair interleaved WITH dual LDS point caches (round-7 redo:
// the centroid read stays a ~120cy LDS broadcast, not a global re-fetch).
// One block = batches A,B; each thread: 8 pts of each in registers. The two
// independent serial chains share each iteration's barrier/merge latency.
// Per-batch op order/tie-breaks verbatim from round-6 -> bit-identical.
// LDS: 2 x 48KB caches + merge slots = ~98KB (1 block/CU, 8 blocks total).
// ---------------------------------------------------------------------------
__global__ __launch_bounds__(512) void fps_kernel(const float* __restrict__ xyz,
                                                  float* __restrict__ new_xyz) {
#pragma clang fp contract(off)
    const int bb = blockIdx.x * 2;
    const int tid = threadIdx.x;
    const int lane = tid & 63, wave = tid >> 6;
    const float* XA = xyz + (size_t)bb * NPTS * 3;
    const float* XB = XA + (size_t)NPTS * 3;
    float* outA = new_xyz + (size_t)bb * NPOINT * 3;
    float* outB = outA + (size_t)NPOINT * 3;

    __shared__ float xsA[NPTS], ysA[NPTS], zsA[NPTS];   // 48 KB
    __shared__ float xsB[NPTS], ysB[NPTS], zsB[NPTS];   // 48 KB
    __shared__ unsigned long long wredA[2][8];
    __shared__ unsigned long long wredB[2][8];

    float pxA[8], pyA[8], pzA[8], ddA[8];
    float pxB[8], pyB[8], pzB[8], ddB[8];
    unsigned idneg[8];
#pragma unroll
    for (int k = 0; k < 8; ++k) {
        const int i = tid + k * 512;
        pxA[k] = XA[i * 3 + 0]; pyA[k] = XA[i * 3 + 1]; pzA[k] = XA[i * 3 + 2];
        pxB[k] = XB[i * 3 + 0]; pyB[k] = XB[i * 3 + 1]; pzB[k] = XB[i * 3 + 2];
        ddA[k] = 1e10f; ddB[k] = 1e10f;
        idneg[k] = (unsigned)(4095 - i);
        xsA[i] = pxA[k]; ysA[i] = pyA[k]; zsA[i] = pzA[k];
        xsB[i] = pxB[k]; ysB[i] = pyB[k]; zsB[i] = pzB[k];
    }
    __syncthreads();

    int farA = 0, farB = 0;
    for (int it = 0; it < NPOINT; ++it) {
        const float cxA = xsA[farA], cyA = ysA[farA], czA = zsA[farA];
        const float cxB = xsB[farB], cyB = ysB[farB], czB = zsB[farB];
        if (tid == 0) {
            outA[it * 3 + 0] = cxA; outA[it * 3 + 1] = cyA; outA[it * 3 + 2] = czA;
            outB[it * 3 + 0] = cxB; outB[it * 3 + 1] = cyB; outB[it * 3 + 2] = czB;
        }

        float bvA = -1.0f; unsigned biA = 0;
        float bvB = -1.0f; unsigned biB = 0;
#pragma unroll
        for (int k = 0; k < 8; ++k) {
            {
                const float dx = pxA[k] - cxA, dy = pyA[k] - cyA, dz = pzA[k] - czA;
                const float dist = (dx * dx + dy * dy) + dz * dz;
                const float nd = fminf(ddA[k], dist);
                ddA[k] = nd;
                const bool gt = nd > bvA;
                bvA = gt ? nd : bvA;
                biA = gt ? idneg[k] : biA;
            }
            {
                const float dx = pxB[k] - cxB, dy = pyB[k] - cyB, dz = pzB[k] - czB;
                const float dist = (dx * dx + dy * dy) + dz * dz;
                const float nd = fminf(ddB[k], dist);
                ddB[k] = nd;
                const bool gt = nd > bvB;
                bvB = gt ? nd : bvB;
                biB = gt ? idneg[k] : biB;
            }
        }
        unsigned long long bestA =
            ((unsigned long long)__float_as_uint(bvA) << 32) | biA;
        unsigned long long bestB =
            ((unsigned long long)__float_as_uint(bvB) << 32) | biB;
        bestA = dpp_max64_to_lane63(bestA);
        bestB = dpp_max64_to_lane63(bestB);
        if (lane == 63) {
            wredA[it & 1][wave] = bestA;
            wredB[it & 1][wave] = bestB;
        }
        __syncthreads();
        unsigned long long gA = wredA[it & 1][0];
        unsigned long long gB = wredB[it & 1][0];
#pragma unroll
        for (int w = 1; w < 8; ++w) {
            const unsigned long long oA = wredA[it & 1][w];
            const unsigned long long oB = wredB[it & 1][w];
            gA = oA > gA ? oA : gA;
            gB = oB > gB ? oB : gB;
        }
        farA = 4095 - (int)(gA & 0xFFFFFFFFull);
        farB = 4095 - (int)(gB & 0xFFFFFFFFull);
    }
}

// ---------------------------------------------------------------------------
// K2: k-nearest (unchanged — DPP extraction).
// ---------------------------------------------------------------------------
__global__ __launch_bounds__(256) void knn_kernel(const float* __restrict__ xyz,
                                                  const float* __restrict__ new_xyz,
                                                  int* __restrict__ idx) {
#pragma clang fp contract(off)
    const int m = blockIdx.x, b = blockIdx.y;
    const int tid = threadIdx.x;
    const int lane = tid & 63, wave = tid >> 6;
    const float* X = xyz + (size_t)b * NPTS * 3;
    const float* c = new_xyz + ((size_t)b * NPOINT + m) * 3;
    const float cx = c[0], cy = c[1], cz = c[2];
    const float sqc = (cx * cx + cy * cy) + cz * cz;

    unsigned long long key[16];
#pragma unroll
    for (int k = 0; k < 16; ++k) {
        const int i = wave * 1024 + k * 64 + lane;
        const float x = X[i * 3 + 0];
        const float y = X[i * 3 + 1];
        const float z = X[i * 3 + 2];
        const float sqi = (x * x + y * y) + z * z;
        const float dot = (cx * x + cy * y) + cz * z;
        const float d2 = (sqc + sqi) - 2.0f * dot;
        const unsigned u = __float_as_uint(d2);
        const unsigned s = u ^ (unsigned)(((int)u >> 31) | 0x80000000);
        key[k] = ((unsigned long long)s << 32) | (unsigned)i;
    }

    __shared__ unsigned long long wk[128];

    for (int j = 0; j < NSAMPLE; ++j) {
        unsigned long long best = key[0];
#pragma unroll
        for (int k = 1; k < 16; ++k) best = key[k] < best ? key[k] : best;
        best = dpp_min64_to_lane63(best);
        const unsigned long long bestAll = readlane63_u64(best);
        if (lane == 0) wk[wave * 32 + j] = bestAll;
#pragma unroll
        for (int k = 0; k < 16; ++k)
            key[k] = (key[k] == bestAll) ? ~0ull : key[k];
    }
    __syncthreads();

    if (wave == 0) {
        int* out = idx + ((size_t)b * NPOINT + m) * NSAMPLE;
        unsigned long long a = wk[lane], bb = wk[64 + lane];
        for (int j = 0; j < NSAMPLE; ++j) {
            unsigned long long best = a < bb ? a : bb;
            best = dpp_min64_to_lane63(best);
            const unsigned long long bestAll = readlane63_u64(best);
            if (lane == 0) out[j] = (int)(bestAll & 0xFFFFFFFFull);
            a  = (a  == bestAll) ? ~0ull : a;
            bb = (bb == bestAll) ? ~0ull : bb;
        }
    }
}

// ---------------------------------------------------------------------------
// K3: P1 = points @ w0[:,3:]^T per raw point (unchanged).
// ---------------------------------------------------------------------------
__global__ __launch_bounds__(256) void p1_kernel(const float* __restrict__ points,
                                                 const float* __restrict__ w0,
                                                 float* __restrict__ P1) {
    const int tid = threadIdx.x;
    const int ch = tid & 63, pl = tid >> 6;
    __shared__ float wsm[64 * 65];
    __shared__ float inb[4][65];
    for (int t = tid; t < 64 * 64; t += 256)
        wsm[(t >> 6) * 65 + (t & 63)] = w0[(t >> 6) * 67 + 3 + (t & 63)];
    __syncthreads();
    const int base = blockIdx.x * 256;
    for (int t = 0; t < 64; ++t) {
        const int q = base + t * 4 + pl;
        inb[pl][ch] = points[(size_t)q * 64 + ch];
        __syncthreads();
        float acc = 0.f;
#pragma unroll
        for (int ic = 0; ic < 64; ++ic)
            acc = fmaf(wsm[ch * 65 + ic], inb[pl][ic], acc);
        P1[(size_t)q * 64 + ch] = acc;
        __syncthreads();
    }
}

__device__ __forceinline__ float z0_calc(float p1v, float bb, float wx0, float wx1,
                                         float wx2, float dx, float dy, float dz) {
    return fmaf(wx2, dz, fmaf(wx1, dy, fmaf(wx0, dx, p1v + bb)));
}

// ---------------------------------------------------------------------------
// K4: stats of layer-0 pre-BN output (unchanged).
// ---------------------------------------------------------------------------
__global__ __launch_bounds__(256) void stats0_kernel(
        const float* __restrict__ xyz, const float* __restrict__ new_xyz,
        const int* __restrict__ idx, const float* __restrict__ P1,
        const float* __restrict__ w0, const float* __restrict__ b0,
        float* __restrict__ stats_out) {
    const int tid = threadIdx.x;
    const int ch = tid & 63, pl = tid >> 6;
    const float wx0 = w0[ch * 67 + 0], wx1 = w0[ch * 67 + 1], wx2 = w0[ch * 67 + 2];
    const float bb0 = b0[ch];
    __shared__ float dls[4][4];
    __shared__ float red[512];
    float sl = 0.f, sq = 0.f;
    const int base = blockIdx.x * 256;
    for (int t = 0; t < 64; ++t) {
        const int p = base + t * 4 + pl;
        const int i = idx[p];
        const int bm = p >> 5;
        const int b  = bm >> 10;
        if (ch < 3)
            dls[pl][ch] = xyz[(((size_t)(b << 12)) + i) * 3 + ch]
                        - new_xyz[(size_t)bm * 3 + ch];
        __syncthreads();
        const float z = z0_calc(P1[(((size_t)(b << 12)) + i) * 64 + ch], bb0,
                                wx0, wx1, wx2, dls[pl][0], dls[pl][1], dls[pl][2]);
        sl += z; sq += z * z;
        __syncthreads();
    }
    red[tid] = sl; red[256 + tid] = sq;
    __syncthreads();
    if (pl == 0) {
        atomicAdd(&stats_out[ch],
                  red[ch] + red[64 + ch] + red[128 + ch] + red[192 + ch]);
        atomicAdd(&stats_out[64 + ch],
                  red[256 + ch] + red[256 + 64 + ch] + red[256 + 128 + ch] + red[256 + 192 + ch]);
    }
}

// ---------------------------------------------------------------------------
// K5: conv1 with REGISTER weights + float4 broadcast input reads (unchanged).
// ---------------------------------------------------------------------------
template<bool STORE>
__global__ __launch_bounds__(256) void conv1_kernel(
        const float* __restrict__ xyz, const float* __restrict__ new_xyz,
        const int* __restrict__ idx, const float* __restrict__ P1,
        const float* __restrict__ w0, const float* __restrict__ b0,
        const float* __restrict__ stats1,
        const float* __restrict__ g0, const float* __restrict__ be0,
        const float* __restrict__ w1, const float* __restrict__ b1,
        __hip_bfloat16* __restrict__ Z2, float* __restrict__ stats_out) {
    const int tid = threadIdx.x;
    const int ch = tid & 63, pl = tid >> 6;
    __shared__ float w1ld[64 * 65];
    __shared__ float inb1[4][68];   // stride 68 -> rows 16B-aligned
    __shared__ float dls[4][4];
    __shared__ float red[512];
    for (int t = tid; t < 64 * 64; t += 256)
        w1ld[(t >> 6) * 65 + (t & 63)] = w1[t];
    __syncthreads();
    float wreg[64];
#pragma unroll
    for (int ic = 0; ic < 64; ++ic) wreg[ic] = w1ld[ch * 65 + ic];

    const float wx0 = w0[ch * 67 + 0], wx1 = w0[ch * 67 + 1], wx2 = w0[ch * 67 + 2];
    const float bb0 = b0[ch];
    const float mn = stats1[ch] * INV_NTOT;
    const float vr = stats1[64 + ch] * INV_NTOT - mn * mn;
    const float sc0 = g0[ch] * rsqrtf(vr + BN_EPS);
    const float sh0 = be0[ch] - mn * sc0;
    const float bb1 = b1[ch];
    float sl = 0.f, sq = 0.f;

    const int base = blockIdx.x * 256;
    for (int t = 0; t < 64; ++t) {
        const int p = base + t * 4 + pl;
        const int i = idx[p];
        const int bm = p >> 5;
        const int b  = bm >> 10;
        if (ch < 3)
            dls[pl][ch] = xyz[(((size_t)(b << 12)) + i) * 3 + ch]
                        - new_xyz[(size_t)bm * 3 + ch];
        __syncthreads();
        const float z0 = z0_calc(P1[(((size_t)(b << 12)) + i) * 64 + ch], bb0,
                                 wx0, wx1, wx2, dls[pl][0], dls[pl][1], dls[pl][2]);
        inb1[pl][ch] = fmaxf(fmaf(z0, sc0, sh0), 0.f);
        __syncthreads();
        const float4* row = (const float4*)&inb1[pl][0];
        float z1 = bb1;
#pragma unroll
        for (int ic4 = 0; ic4 < 16; ++ic4) {
            const float4 v = row[ic4];
            z1 = fmaf(wreg[4 * ic4 + 0], v.x, z1);
            z1 = fmaf(wreg[4 * ic4 + 1], v.y, z1);
            z1 = fmaf(wreg[4 * ic4 + 2], v.z, z1);
            z1 = fmaf(wreg[4 * ic4 + 3], v.w, z1);
        }
        if (STORE) Z2[(size_t)p * 64 + ch] = __float2bfloat16(z1);
        sl += z1; sq += z1 * z1;
        __syncthreads();
    }
    red[tid] = sl; red[256 + tid] = sq;
    __syncthreads();
    if (pl == 0) {
        atomicAdd(&stats_out[ch],
                  red[ch] + red[64 + ch] + red[128 + ch] + red[192 + ch]);
        atomicAdd(&stats_out[64 + ch],
                  red[256 + ch] + red[256 + 64 + ch] + red[256 + 128 + ch] + red[256 + 192 + ch]);
    }
}

// ---------------------------------------------------------------------------
// K6: conv2 SINGLE pass (unchanged): register weights, stats3 + z3 max/min.
// ---------------------------------------------------------------------------
template<bool RECOMP>
__global__ __launch_bounds__(256) void conv2s_kernel(
        const float* __restrict__ xyz, const float* __restrict__ new_xyz,
        const int* __restrict__ idx, const float* __restrict__ P1,
        const float* __restrict__ w0, const float* __restrict__ b0,
        const float* __restrict__ stats1,
        const float* __restrict__ g0, const float* __restrict__ be0,
        const float* __restrict__ w1, const float* __restrict__ b1,
        const __hip_bfloat16* __restrict__ Z2,
        const float* __restrict__ stats2,
        const float* __restrict__ g1, const float* __restrict__ be1,
        const float* __restrict__ w2, const float* __restrict__ b2,
        float* __restrict__ stats_out,
        float* __restrict__ Z3max, float* __restrict__ Z3min) {
    const int tid = threadIdx.x;
    const int ch = tid & 63,  pl = tid >> 6;
    const int c2 = tid & 127, p2 = tid >> 7;

    __shared__ float w2ld[128 * 65];
    __shared__ float w1sm[RECOMP ? 64 * 65 : 1];
    __shared__ float inb1[RECOMP ? 4 : 1][68];
    __shared__ float inb2[4][68];
    __shared__ float dls[4][4];
    __shared__ float red[512];
    __shared__ float pmax[2][128];
    __shared__ float pmin[2][128];

    for (int t = tid; t < 128 * 64; t += 256)
        w2ld[(t >> 6) * 65 + (t & 63)] = w2[t];
    if (RECOMP)
        for (int t = tid; t < 64 * 64; t += 256)
            w1sm[(t >> 6) * 65 + (t & 63)] = w1[t];
    __syncthreads();
    float wreg[64];
#pragma unroll
    for (int ic = 0; ic < 64; ++ic) wreg[ic] = w2ld[c2 * 65 + ic];

    float wx0 = 0.f, wx1 = 0.f, wx2 = 0.f, bb0 = 0.f, sc0 = 0.f, sh0 = 0.f, bb1 = 0.f;
    if (RECOMP) {
        wx0 = w0[ch * 67 + 0]; wx1 = w0[ch * 67 + 1]; wx2 = w0[ch * 67 + 2];
        bb0 = b0[ch];
        const float mn = stats1[ch] * INV_NTOT;
        const float vr = stats1[64 + ch] * INV_NTOT - mn * mn;
        sc0 = g0[ch] * rsqrtf(vr + BN_EPS);
        sh0 = be0[ch] - mn * sc0;
        bb1 = b1[ch];
    }
    float sc1, sh1;
    {
        const float mn = stats2[ch] * INV_NTOT;
        const float vr = stats2[64 + ch] * INV_NTOT - mn * mn;
        sc1 = g1[ch] * rsqrtf(vr + BN_EPS);
        sh1 = be1[ch] - mn * sc1;
    }
    const float bb2 = b2[c2];
    float sl = 0.f, sq = 0.f, mx = -FLT_MAX, mnv = FLT_MAX;

    const int base = blockIdx.x * 256;
    for (int t = 0; t < 64; ++t) {
        const int p = base + t * 4 + pl;
        if (RECOMP) {
            const int i = idx[p];
            const int bm = p >> 5;
            const int b  = bm >> 10;
            if (ch < 3)
                dls[pl][ch] = xyz[(((size_t)(b << 12)) + i) * 3 + ch]
                            - new_xyz[(size_t)bm * 3 + ch];
            __syncthreads();
            const float z0 = z0_calc(P1[(((size_t)(b << 12)) + i) * 64 + ch], bb0,
                                     wx0, wx1, wx2, dls[pl][0], dls[pl][1], dls[pl][2]);
            inb1[pl][ch] = fmaxf(fmaf(z0, sc0, sh0), 0.f);
            __syncthreads();
            const float4* row1 = (const float4*)&inb1[pl][0];
            float z1 = bb1;
#pragma unroll
            for (int ic4 = 0; ic4 < 16; ++ic4) {
                const float4 v = row1[ic4];
                z1 = fmaf(w1sm[ch * 65 + 4 * ic4 + 0], v.x, z1);
                z1 = fmaf(w1sm[ch * 65 + 4 * ic4 + 1], v.y, z1);
                z1 = fmaf(w1sm[ch * 65 + 4 * ic4 + 2], v.z, z1);
                z1 = fmaf(w1sm[ch * 65 + 4 * ic4 + 3], v.w, z1);
            }
            inb2[pl][ch] = fmaxf(fmaf(z1, sc1, sh1), 0.f);
        } else {
            const float z1 = __bfloat162float(Z2[(size_t)p * 64 + ch]);
            inb2[pl][ch] = fmaxf(fmaf(z1, sc1, sh1), 0.f);
        }
        __syncthreads();

#pragma unroll
        for (int q = 0; q < 2; ++q) {
            const int pr = q * 2 + p2;
            const float4* row2 = (const float4*)&inb2[pr][0];
            float z2 = bb2;
#pragma unroll
            for (int ic4 = 0; ic4 < 16; ++ic4) {
                const float4 v = row2[ic4];
                z2 = fmaf(wreg[4 * ic4 + 0], v.x, z2);
                z2 = fmaf(wreg[4 * ic4 + 1], v.y, z2);
                z2 = fmaf(wreg[4 * ic4 + 2], v.z, z2);
                z2 = fmaf(wreg[4 * ic4 + 3], v.w, z2);
            }
            sl += z2; sq += z2 * z2;
            mx = fmaxf(mx, z2); mnv = fminf(mnv, z2);
        }
        if ((t & 7) == 7) {                 // 32-sample group complete
            pmax[p2][c2] = mx; pmin[p2][c2] = mnv;
            __syncthreads();
            if (p2 == 0) {
                const int bm = (base >> 5) + (t >> 3);
                Z3max[(size_t)bm * 128 + c2] = fmaxf(pmax[0][c2], pmax[1][c2]);
                Z3min[(size_t)bm * 128 + c2] = fminf(pmin[0][c2], pmin[1][c2]);
            }
            mx = -FLT_MAX; mnv = FLT_MAX;
        }
        __syncthreads();
    }

    red[tid] = sl; red[256 + tid] = sq;
    __syncthreads();
    if (tid < 128) {
        atomicAdd(&stats_out[tid],       red[tid] + red[128 + tid]);
        atomicAdd(&stats_out[128 + tid], red[256 + tid] + red[256 + 128 + tid]);
    }
}

// ---------------------------------------------------------------------------
// K7: epilogue — BN2+ReLU on the selected z3 extreme, transposed write.
// ---------------------------------------------------------------------------
__global__ __launch_bounds__(256) void pool_mm_kernel(
        const float* __restrict__ Z3max, const float* __restrict__ Z3min,
        const float* __restrict__ stats,
        const float* __restrict__ g, const float* __restrict__ beta,
        float* __restrict__ outNP) {
    const int tid = threadIdx.x;
    const int mtile = blockIdx.x;    // 0..31
    const int b = blockIdx.y;        // 0..15
    const int ch = tid & 127, mh = tid >> 7;

    const float mean  = stats[ch] * INV_NTOT;
    const float var   = stats[128 + ch] * INV_NTOT - mean * mean;
    const float scale = g[ch] * rsqrtf(var + BN_EPS);
    const float shift = beta[ch] - mean * scale;

    __shared__ float pool[32][129];

    for (int pass = 0; pass < 16; ++pass) {
        const int ml = pass * 2 + mh;
        const size_t bm = (size_t)b * NPOINT + mtile * 32 + ml;
        const float zx = Z3max[bm * 128 + ch];
        const float zn = Z3min[bm * 128 + ch];
        const float zsel = (scale >= 0.f) ? zx : zn;
        pool[ml][ch] = fmaxf(fmaf(zsel, scale, shift), 0.f);
    }
    __syncthreads();

#pragma unroll
    for (int r = 0; r < 16; ++r) {
        const int o  = r * 256 + tid;
        const int ml = o & 31;
        const int c2 = o >> 5;
        outNP[((size_t)b * 128 + c2) * NPOINT + mtile * 32 + ml] = pool[ml][c2];
    }
}

// ---------------------------------------------------------------------------
// Legacy tier-C fallback (conv2 double pass) — unchanged.
// ---------------------------------------------------------------------------
template<bool RECOMP, bool FINAL>
__global__ __launch_bounds__(256) void conv2_kernel(
        const float* __restrict__ xyz, const float* __restrict__ new_xyz,
        const int* __restrict__ idx, const float* __restrict__ P1,
        const float* __restrict__ w0, const float* __restrict__ b0,
        const float* __restrict__ stats1,
        const float* __restrict__ g0, const float* __restrict__ be0,
        const float* __restrict__ w1, const float* __restrict__ b1,
        const __hip_bfloat16* __restrict__ Z2,
        const float* __restrict__ stats2,
        const float* __restrict__ g1, const float* __restrict__ be1,
        const float* __restrict__ w2, const float* __restrict__ b2,
        const float* __restrict__ stats3,
        const float* __restrict__ g2, const float* __restrict__ be2,
        float* __restrict__ stats_out, float* __restrict__ outNP) {
    const int tid = threadIdx.x;
    const int ch = tid & 63,  pl = tid >> 6;
    const int c2 = tid & 127, p2 = tid >> 7;

    __shared__ float w2sm[128 * 65];
    __shared__ float w1sm[RECOMP ? 64 * 65 : 1];
    __shared__ float inb1[RECOMP ? 4 : 1][65];
    __shared__ float inb2[4][65];
    __shared__ float dls[4][4];
    __shared__ float red[FINAL ? 1 : 512];
    __shared__ float pmax[FINAL ? 2 : 1][128];
    __shared__ float poolbuf[FINAL ? 8 : 1][129];

    for (int t = tid; t < 128 * 64; t += 256)
        w2sm[(t >> 6) * 65 + (t & 63)] = w2[t];
    if (RECOMP)
        for (int t = tid; t < 64 * 64; t += 256)
            w1sm[(t >> 6) * 65 + (t & 63)] = w1[t];

    float wx0 = 0.f, wx1 = 0.f, wx2 = 0.f, bb0 = 0.f, sc0 = 0.f, sh0 = 0.f, bb1 = 0.f;
    if (RECOMP) {
        wx0 = w0[ch * 67 + 0]; wx1 = w0[ch * 67 + 1]; wx2 = w0[ch * 67 + 2];
        bb0 = b0[ch];
        const float mn = stats1[ch] * INV_NTOT;
        const float vr = stats1[64 + ch] * INV_NTOT - mn * mn;
        sc0 = g0[ch] * rsqrtf(vr + BN_EPS);
        sh0 = be0[ch] - mn * sc0;
        bb1 = b1[ch];
    }
    float sc1, sh1;
    {
        const float mn = stats2[ch] * INV_NTOT;
        const float vr = stats2[64 + ch] * INV_NTOT - mn * mn;
        sc1 = g1[ch] * rsqrtf(vr + BN_EPS);
        sh1 = be1[ch] - mn * sc1;
    }
    const float bb2 = b2[c2];
    float sc2 = 0.f, sh2 = 0.f;
    if (FINAL) {
        const float mn = stats3[c2] * INV_NTOT;
        const float vr = stats3[128 + c2] * INV_NTOT - mn * mn;
        sc2 = g2[c2] * rsqrtf(vr + BN_EPS);
        sh2 = be2[c2] - mn * sc2;
    }
    float sl = 0.f, sq = 0.f, mx = -FLT_MAX;
    __syncthreads();

    const int base = blockIdx.x * 256;
    for (int t = 0; t < 64; ++t) {
        const int p = base + t * 4 + pl;
        if (RECOMP) {
            const int i = idx[p];
            const int bm = p >> 5;
            const int b  = bm >> 10;
            if (ch < 3)
                dls[pl][ch] = xyz[(((size_t)(b << 12)) + i) * 3 + ch]
                            - new_xyz[(size_t)bm * 3 + ch];
            __syncthreads();
            const float z0 = z0_calc(P1[(((size_t)(b << 12)) + i) * 64 + ch], bb0,
                                     wx0, wx1, wx2, dls[pl][0], dls[pl][1], dls[pl][2]);
            inb1[pl][ch] = fmaxf(fmaf(z0, sc0, sh0), 0.f);
            __syncthreads();
            float z1 = bb1;
#pragma unroll
            for (int ic = 0; ic < 64; ++ic)
                z1 = fmaf(w1sm[ch * 65 + ic], inb1[pl][ic], z1);
            inb2[pl][ch] = fmaxf(fmaf(z1, sc1, sh1), 0.f);
        } else {
            const float z1 = __bfloat162float(Z2[(size_t)p * 64 + ch]);
            inb2[pl][ch] = fmaxf(fmaf(z1, sc1, sh1), 0.f);
        }
        __syncthreads();

#pragma unroll
        for (int q = 0; q < 2; ++q) {
            const int pr = q * 2 + p2;
            float z2 = bb2;
#pragma unroll
            for (int ic = 0; ic < 64; ++ic)
                z2 = fmaf(w2sm[c2 * 65 + ic], inb2[pr][ic], z2);
            if (FINAL) {
                mx = fmaxf(mx, fmaxf(fmaf(z2, sc2, sh2), 0.f));
            } else {
                sl += z2; sq += z2 * z2;
            }
        }
        if (FINAL && ((t & 7) == 7)) {
            pmax[p2][c2] = mx;
            __syncthreads();
            if (p2 == 0)
                poolbuf[t >> 3][c2] = fmaxf(pmax[0][c2], pmax[1][c2]);
            mx = -FLT_MAX;
        }
        __syncthreads();
    }

    if (FINAL) {
        const int b  = base >> 15;
        const int m0 = (base >> 5) & 1023;
#pragma unroll
        for (int r = 0; r < 4; ++r) {
            const int o   = r * 256 + tid;
            const int row = o >> 3;
            const int gg  = o & 7;
            outNP[((size_t)(b * 128 + row)) * 1024 + m0 + gg] = poolbuf[gg][row];
        }
    } else {
        red[tid] = sl; red[256 + tid] = sq;
        __syncthreads();
        if (tid < 128) {
            atomicAdd(&stats_out[tid],       red[tid] + red[128 + tid]);
            atomicAdd(&stats_out[128 + tid], red[256 + tid] + red[256 + 128 + tid]);
        }
    }
}

// ---------------------------------------------------------------------------
extern "C" void kernel_launch(void* const* d_in, const int* in_sizes, int n_in,
                              void* d_out, int out_size, void* d_ws, size_t ws_size,
                              hipStream_t stream) {
    const float* xyz    = (const float*)d_in[0];
    const float* points = (const float*)d_in[1];
    const float* w0  = (const float*)d_in[2];
    const float* b0  = (const float*)d_in[3];
    const float* g0  = (const float*)d_in[4];
    const float* be0 = (const float*)d_in[5];
    const float* w1  = (const float*)d_in[6];
    const float* b1  = (const float*)d_in[7];
    const float* g1  = (const float*)d_in[8];
    const float* be1 = (const float*)d_in[9];
    const float* w2  = (const float*)d_in[10];
    const float* b2  = (const float*)d_in[11];
    const float* g2  = (const float*)d_in[12];
    const float* be2 = (const float*)d_in[13];

    float* out        = (float*)d_out;
    float* new_xyz    = out;
    float* new_points = out + (size_t)BATCH * NPOINT * 3;

    // ws: idx 2MB | stats 4KB | P1 16MB | Z3max 8MB | Z3min 8MB | Z2 64MB
    char* ws = (char*)d_ws;
    int*   idx   = (int*)ws;
    float* stats = (float*)(ws + (size_t)(2u << 20));
    float* P1    = (float*)(ws + (size_t)(2u << 20) + 4096);
    const size_t offMM = (size_t)(2u << 20) + 4096 + (size_t)BATCH * NPTS * 64 * 4;
    float* Z3max = (float*)(ws + offMM);
    float* Z3min = Z3max + (size_t)BATCH * NPOINT * 128;
    const size_t offZ2 = offMM + (size_t)BATCH * NPOINT * 128 * 4 * 2;
    __hip_bfloat16* Z2 = (__hip_bfloat16*)(ws + offZ2);

    const bool tierA = ws_size >= offZ2 + (size_t)NTOT * 64 * 2;  // ~98 MB
    const bool tierB = ws_size >= offZ2;                          // ~34 MB

    float* stats1 = stats;
    float* stats2 = stats + 128;
    float* stats3 = stats + 256;

    init_stats_kernel<<<1, 512, 0, stream>>>(stats);
    p1_kernel<<<BATCH * NPTS / 256, 256, 0, stream>>>(points, w0, P1);
    fps_kernel<<<BATCH / 2, 512, 0, stream>>>(xyz, new_xyz);
    knn_kernel<<<dim3(NPOINT, BATCH), 256, 0, stream>>>(xyz, new_xyz, idx);
    stats0_kernel<<<NTOT / 256, 256, 0, stream>>>(xyz, new_xyz, idx, P1,
                                                  w0, b0, stats1);
    if (tierA) {
        conv1_kernel<true><<<NTOT / 256, 256, 0, stream>>>(
            xyz, new_xyz, idx, P1, w0, b0, stats1, g0, be0, w1, b1, Z2, stats2);
        conv2s_kernel<false><<<NTOT / 256, 256, 0, stream>>>(
            xyz, new_xyz, idx, P1, w0, b0, stats1, g0, be0, w1, b1, Z2,
            stats2, g1, be1, w2, b2, stats3, Z3max, Z3min);
        pool_mm_kernel<<<dim3(32, BATCH), 256, 0, stream>>>(
            Z3max, Z3min, stats3, g2, be2, new_points);
    } else if (tierB) {
        conv1_kernel<false><<<NTOT / 256, 256, 0, stream>>>(
            xyz, new_xyz, idx, P1, w0, b0, stats1, g0, be0, w1, b1, Z2, stats2);
        conv2s_kernel<true><<<NTOT / 256, 256, 0, stream>>>(
            xyz, new_xyz, idx, P1, w0, b0, stats1, g0, be0, w1, b1, Z2,
            stats2, g1, be1, w2, b2, stats3, Z3max, Z3min);
        pool_mm_kernel<<<dim3(32, BATCH), 256, 0, stream>>>(
            Z3max, Z3min, stats3, g2, be2, new_points);
    } else {
        conv1_kernel<false><<<NTOT / 256, 256, 0, stream>>>(
            xyz, new_xyz, idx, P1, w0, b0, stats1, g0, be0, w1, b1, Z2, stats2);
        conv2_kernel<true, false><<<NTOT / 256, 256, 0, stream>>>(
            xyz, new_xyz, idx, P1, w0, b0, stats1, g0, be0, w1, b1, Z2,
            stats2, g1, be1, w2, b2, stats3, g2, be2, stats3, new_points);
        conv2_kernel<true, true><<<NTOT / 256, 256, 0, stream>>>(
            xyz, new_xyz, idx, P1, w0, b0, stats1, g0, be0, w1, b1, Z2,
            stats2, g1, be1, w2, b2, stats3, g2, be2, stats3, new_points);
    }
}

// Round 10
// 1985.662 us; speedup vs baseline: 1.4185x; 1.4185x over previous
//
#include <hip/hip_runtime.h>
#include <hip/hip_bf16.h>
#include <float.h>

#define NPTS    4096
#define NPOINT  1024
#define NSAMPLE 32
#define BATCH   16
#define NTOT    (BATCH * NPOINT * NSAMPLE)   // 524288 gathered pairs
#define INV_NTOT (1.0f / 524288.0f)
#define BN_EPS  1e-5f

// ---------------------------------------------------------------------------
// DPP wave-64 reduction helpers (pure VALU — no LDS-pipe bpermute/swizzle).
// ---------------------------------------------------------------------------
template<int CTRL, int OLD>
__device__ __forceinline__ unsigned long long dpp_move_u64(unsigned long long v) {
    const int lo = __builtin_amdgcn_update_dpp(OLD, (int)(unsigned)v,        CTRL, 0xF, 0xF, false);
    const int hi = __builtin_amdgcn_update_dpp(OLD, (int)(unsigned)(v >> 32), CTRL, 0xF, 0xF, false);
    return ((unsigned long long)(unsigned)hi << 32) | (unsigned)lo;
}

__device__ __forceinline__ unsigned long long dpp_max64_to_lane63(unsigned long long v) {
    unsigned long long o;
    o = dpp_move_u64<0x111, 0>(v); v = o > v ? o : v;
    o = dpp_move_u64<0x112, 0>(v); v = o > v ? o : v;
    o = dpp_move_u64<0x114, 0>(v); v = o > v ? o : v;
    o = dpp_move_u64<0x118, 0>(v); v = o > v ? o : v;
    o = dpp_move_u64<0x142, 0>(v); v = o > v ? o : v;
    o = dpp_move_u64<0x143, 0>(v); v = o > v ? o : v;
    return v;
}

__device__ __forceinline__ unsigned long long dpp_min64_to_lane63(unsigned long long v) {
    unsigned long long o;
    o = dpp_move_u64<0x111, -1>(v); v = o < v ? o : v;
    o = dpp_move_u64<0x112, -1>(v); v = o < v ? o : v;
    o = dpp_move_u64<0x114, -1>(v); v = o < v ? o : v;
    o = dpp_move_u64<0x118, -1>(v); v = o < v ? o : v;
    o = dpp_move_u64<0x142, -1>(v); v = o < v ? o : v;
    o = dpp_move_u64<0x143, -1>(v); v = o < v ? o : v;
    return v;
}

__device__ __forceinline__ unsigned long long readlane63_u64(unsigned long long v) {
    const unsigned lo = (unsigned)__builtin_amdgcn_readlane((int)(unsigned)v, 63);
    const unsigned hi = (unsigned)__builtin_amdgcn_readlane((int)(unsigned)(v >> 32), 63);
    return ((unsigned long long)hi << 32) | lo;
}

// ---------------------------------------------------------------------------
__global__ void init_stats_kernel(float* __restrict__ stats) {
    stats[threadIdx.x] = 0.0f;
}

// ---------------------------------------------------------------------------
// K1: FPS — round-6 version verbatim (809 µs, best measured).
// One block per batch, 512 thr, 8 pts/thread, LDS point cache, one barrier
// per iteration, DPP wave reduce. key = bits(d)<<32 | (4095-i).
// ---------------------------------------------------------------------------
__global__ __launch_bounds__(512) void fps_kernel(const float* __restrict__ xyz,
                                                  float* __restrict__ new_xyz) {
#pragma clang fp contract(off)
    const int b = blockIdx.x, tid = threadIdx.x;
    const int lane = tid & 63, wave = tid >> 6;
    const float* X = xyz + (size_t)b * NPTS * 3;
    float* outC = new_xyz + (size_t)b * NPOINT * 3;

    __shared__ float xs[NPTS], ys[NPTS], zs[NPTS];
    __shared__ unsigned long long wred[2][8];

    float px[8], py[8], pz[8], dd[8];
    unsigned idneg[8];
#pragma unroll
    for (int k = 0; k < 8; ++k) {
        const int i = tid + k * 512;
        px[k] = X[i * 3 + 0]; py[k] = X[i * 3 + 1]; pz[k] = X[i * 3 + 2];
        dd[k] = 1e10f;
        idneg[k] = (unsigned)(4095 - i);
        xs[i] = px[k]; ys[i] = py[k]; zs[i] = pz[k];
    }
    __syncthreads();

    int far = 0;
    for (int it = 0; it < NPOINT; ++it) {
        const float cx = xs[far], cy = ys[far], cz = zs[far];
        if (tid == 0) {
            outC[it * 3 + 0] = cx; outC[it * 3 + 1] = cy; outC[it * 3 + 2] = cz;
        }
        float bv = -1.0f; unsigned biNeg = 0;
#pragma unroll
        for (int k = 0; k < 8; ++k) {
            const float dx = px[k] - cx, dy = py[k] - cy, dz = pz[k] - cz;
            const float dist = (dx * dx + dy * dy) + dz * dz;
            const float nd = fminf(dd[k], dist);
            dd[k] = nd;
            const bool gt = nd > bv;
            bv = gt ? nd : bv;
            biNeg = gt ? idneg[k] : biNeg;
        }
        unsigned long long best =
            ((unsigned long long)__float_as_uint(bv) << 32) | biNeg;
        best = dpp_max64_to_lane63(best);
        if (lane == 63) wred[it & 1][wave] = best;
        __syncthreads();
        unsigned long long g = wred[it & 1][0];
#pragma unroll
        for (int w = 1; w < 8; ++w) {
            const unsigned long long o = wred[it & 1][w];
            g = o > g ? o : g;
        }
        far = 4095 - (int)(g & 0xFFFFFFFFull);
    }
}

// ---------------------------------------------------------------------------
// K2: k-nearest (unchanged — DPP extraction).
// ---------------------------------------------------------------------------
__global__ __launch_bounds__(256) void knn_kernel(const float* __restrict__ xyz,
                                                  const float* __restrict__ new_xyz,
                                                  int* __restrict__ idx) {
#pragma clang fp contract(off)
    const int m = blockIdx.x, b = blockIdx.y;
    const int tid = threadIdx.x;
    const int lane = tid & 63, wave = tid >> 6;
    const float* X = xyz + (size_t)b * NPTS * 3;
    const float* c = new_xyz + ((size_t)b * NPOINT + m) * 3;
    const float cx = c[0], cy = c[1], cz = c[2];
    const float sqc = (cx * cx + cy * cy) + cz * cz;

    unsigned long long key[16];
#pragma unroll
    for (int k = 0; k < 16; ++k) {
        const int i = wave * 1024 + k * 64 + lane;
        const float x = X[i * 3 + 0];
        const float y = X[i * 3 + 1];
        const float z = X[i * 3 + 2];
        const float sqi = (x * x + y * y) + z * z;
        const float dot = (cx * x + cy * y) + cz * z;
        const float d2 = (sqc + sqi) - 2.0f * dot;
        const unsigned u = __float_as_uint(d2);
        const unsigned s = u ^ (unsigned)(((int)u >> 31) | 0x80000000);
        key[k] = ((unsigned long long)s << 32) | (unsigned)i;
    }

    __shared__ unsigned long long wk[128];

    for (int j = 0; j < NSAMPLE; ++j) {
        unsigned long long best = key[0];
#pragma unroll
        for (int k = 1; k < 16; ++k) best = key[k] < best ? key[k] : best;
        best = dpp_min64_to_lane63(best);
        const unsigned long long bestAll = readlane63_u64(best);
        if (lane == 0) wk[wave * 32 + j] = bestAll;
#pragma unroll
        for (int k = 0; k < 16; ++k)
            key[k] = (key[k] == bestAll) ? ~0ull : key[k];
    }
    __syncthreads();

    if (wave == 0) {
        int* out = idx + ((size_t)b * NPOINT + m) * NSAMPLE;
        unsigned long long a = wk[lane], bb = wk[64 + lane];
        for (int j = 0; j < NSAMPLE; ++j) {
            unsigned long long best = a < bb ? a : bb;
            best = dpp_min64_to_lane63(best);
            const unsigned long long bestAll = readlane63_u64(best);
            if (lane == 0) out[j] = (int)(bestAll & 0xFFFFFFFFull);
            a  = (a  == bestAll) ? ~0ull : a;
            bb = (bb == bestAll) ? ~0ull : bb;
        }
    }
}

// ---------------------------------------------------------------------------
// K3: P1 = points @ w0[:,3:]^T — 16-point phases, register weights.
// 2 barriers per 16 points (was 2 per 4). FMA order unchanged.
// ---------------------------------------------------------------------------
__global__ __launch_bounds__(256) void p1_kernel(const float* __restrict__ points,
                                                 const float* __restrict__ w0,
                                                 float* __restrict__ P1) {
    const int tid = threadIdx.x;
    const int ch = tid & 63, pg = tid >> 6;
    __shared__ float wld[64 * 65];
    __shared__ float inb[16][68];
    for (int t = tid; t < 64 * 64; t += 256)
        wld[(t >> 6) * 65 + (t & 63)] = w0[(t >> 6) * 67 + 3 + (t & 63)];
    __syncthreads();
    float wreg[64];
#pragma unroll
    for (int ic = 0; ic < 64; ++ic) wreg[ic] = wld[ch * 65 + ic];

    const int base = blockIdx.x * 256;
    for (int t = 0; t < 16; ++t) {
        const int q0 = base + t * 16;
#pragma unroll
        for (int k = 0; k < 4; ++k) {
            const int pos = pg + k * 4;
            inb[pos][ch] = points[(size_t)(q0 + pos) * 64 + ch];
        }
        __syncthreads();
#pragma unroll
        for (int j = 0; j < 4; ++j) {
            const int pos = pg * 4 + j;
            const float4* row = (const float4*)&inb[pos][0];
            float acc = 0.f;
#pragma unroll
            for (int ic4 = 0; ic4 < 16; ++ic4) {
                const float4 v = row[ic4];
                acc = fmaf(wreg[4 * ic4 + 0], v.x, acc);
                acc = fmaf(wreg[4 * ic4 + 1], v.y, acc);
                acc = fmaf(wreg[4 * ic4 + 2], v.z, acc);
                acc = fmaf(wreg[4 * ic4 + 3], v.w, acc);
            }
            P1[(size_t)(q0 + pos) * 64 + ch] = acc;
        }
        __syncthreads();
    }
}

__device__ __forceinline__ float z0_calc(float p1v, float bb, float wx0, float wx1,
                                         float wx2, float dx, float dy, float dz) {
    return fmaf(wx2, dz, fmaf(wx1, dy, fmaf(wx0, dx, p1v + bb)));
}

// ---------------------------------------------------------------------------
// K4: stats of layer-0 pre-BN output — 16-position phases (2 barriers each).
// ---------------------------------------------------------------------------
__global__ __launch_bounds__(256) void stats0_kernel(
        const float* __restrict__ xyz, const float* __restrict__ new_xyz,
        const int* __restrict__ idx, const float* __restrict__ P1,
        const float* __restrict__ w0, const float* __restrict__ b0,
        float* __restrict__ stats_out) {
    const int tid = threadIdx.x;
    const int ch = tid & 63, pg = tid >> 6;
    const float wx0 = w0[ch * 67 + 0], wx1 = w0[ch * 67 + 1], wx2 = w0[ch * 67 + 2];
    const float bb0 = b0[ch];
    __shared__ float dls[16][4];
    __shared__ int   iidx[16];
    __shared__ float red[512];
    float sl = 0.f, sq = 0.f;
    const int base = blockIdx.x * 256;
    for (int t = 0; t < 16; ++t) {
        const int p0 = base + t * 16;
        if (tid < 48) {
            const int pos = tid / 3, c = tid - pos * 3;
            const int p = p0 + pos;
            const int bm = p >> 5, b = bm >> 10;
            const int i = idx[p];
            dls[pos][c] = xyz[(((size_t)(b << 12)) + i) * 3 + c]
                        - new_xyz[(size_t)bm * 3 + c];
        } else if (tid < 64) {
            iidx[tid - 48] = idx[p0 + tid - 48];
        }
        __syncthreads();
#pragma unroll
        for (int k = 0; k < 4; ++k) {
            const int pos = pg + k * 4;
            const int p = p0 + pos;
            const int bm = p >> 5, b = bm >> 10;
            const int i = iidx[pos];
            const float z = z0_calc(P1[(((size_t)(b << 12)) + i) * 64 + ch], bb0,
                                    wx0, wx1, wx2, dls[pos][0], dls[pos][1], dls[pos][2]);
            sl += z; sq += z * z;
        }
        __syncthreads();
    }
    red[tid] = sl; red[256 + tid] = sq;
    __syncthreads();
    if (pg == 0) {
        atomicAdd(&stats_out[ch],
                  red[ch] + red[64 + ch] + red[128 + ch] + red[192 + ch]);
        atomicAdd(&stats_out[64 + ch],
                  red[256 + ch] + red[256 + 64 + ch] + red[256 + 128 + ch] + red[256 + 192 + ch]);
    }
}

// ---------------------------------------------------------------------------
// K5: conv1 — 16-position phases: A0 (dls/idx stage), A1 (16x64 inb1 slots,
// 4/thread), B (4 outputs x 64 FMA, register weights). 3 barriers per 16 pos
// (was 2 per 4). Per-output FMA order unchanged -> bit-identical z1.
// ---------------------------------------------------------------------------
template<bool STORE>
__global__ __launch_bounds__(256) void conv1_kernel(
        const float* __restrict__ xyz, const float* __restrict__ new_xyz,
        const int* __restrict__ idx, const float* __restrict__ P1,
        const float* __restrict__ w0, const float* __restrict__ b0,
        const float* __restrict__ stats1,
        const float* __restrict__ g0, const float* __restrict__ be0,
        const float* __restrict__ w1, const float* __restrict__ b1,
        __hip_bfloat16* __restrict__ Z2, float* __restrict__ stats_out) {
    const int tid = threadIdx.x;
    const int ch = tid & 63, pg = tid >> 6;
    __shared__ float w1ld[64 * 65];
    __shared__ float inb1[16][68];
    __shared__ float dls[16][4];
    __shared__ int   iidx[16];
    __shared__ float red[512];
    for (int t = tid; t < 64 * 64; t += 256)
        w1ld[(t >> 6) * 65 + (t & 63)] = w1[t];
    __syncthreads();
    float wreg[64];
#pragma unroll
    for (int ic = 0; ic < 64; ++ic) wreg[ic] = w1ld[ch * 65 + ic];

    const float wx0 = w0[ch * 67 + 0], wx1 = w0[ch * 67 + 1], wx2 = w0[ch * 67 + 2];
    const float bb0 = b0[ch];
    const float mn = stats1[ch] * INV_NTOT;
    const float vr = stats1[64 + ch] * INV_NTOT - mn * mn;
    const float sc0 = g0[ch] * rsqrtf(vr + BN_EPS);
    const float sh0 = be0[ch] - mn * sc0;
    const float bb1 = b1[ch];
    float sl = 0.f, sq = 0.f;

    const int base = blockIdx.x * 256;
    for (int t = 0; t < 16; ++t) {
        const int p0 = base + t * 16;
        if (tid < 48) {
            const int pos = tid / 3, c = tid - pos * 3;
            const int p = p0 + pos;
            const int bm = p >> 5, b = bm >> 10;
            const int i = idx[p];
            dls[pos][c] = xyz[(((size_t)(b << 12)) + i) * 3 + c]
                        - new_xyz[(size_t)bm * 3 + c];
        } else if (tid < 64) {
            iidx[tid - 48] = idx[p0 + tid - 48];
        }
        __syncthreads();
#pragma unroll
        for (int k = 0; k < 4; ++k) {
            const int pos = pg + k * 4;
            const int p = p0 + pos;
            const int bm = p >> 5, b = bm >> 10;
            const int i = iidx[pos];
            const float z0 = z0_calc(P1[(((size_t)(b << 12)) + i) * 64 + ch], bb0,
                                     wx0, wx1, wx2, dls[pos][0], dls[pos][1], dls[pos][2]);
            inb1[pos][ch] = fmaxf(fmaf(z0, sc0, sh0), 0.f);
        }
        __syncthreads();
#pragma unroll
        for (int j = 0; j < 4; ++j) {
            const int pos = pg * 4 + j;
            const float4* row = (const float4*)&inb1[pos][0];
            float z1 = bb1;
#pragma unroll
            for (int ic4 = 0; ic4 < 16; ++ic4) {
                const float4 v = row[ic4];
                z1 = fmaf(wreg[4 * ic4 + 0], v.x, z1);
                z1 = fmaf(wreg[4 * ic4 + 1], v.y, z1);
                z1 = fmaf(wreg[4 * ic4 + 2], v.z, z1);
                z1 = fmaf(wreg[4 * ic4 + 3], v.w, z1);
            }
            if (STORE) Z2[(size_t)(p0 + pos) * 64 + ch] = __float2bfloat16(z1);
            sl += z1; sq += z1 * z1;
        }
        __syncthreads();
    }
    red[tid] = sl; red[256 + tid] = sq;
    __syncthreads();
    if (pg == 0) {
        atomicAdd(&stats_out[ch],
                  red[ch] + red[64 + ch] + red[128 + ch] + red[192 + ch]);
        atomicAdd(&stats_out[64 + ch],
                  red[256 + ch] + red[256 + 64 + ch] + red[256 + 128 + ch] + red[256 + 192 + ch]);
    }
}

// ---------------------------------------------------------------------------
// K6: conv2 single pass — 16-position phases; stats3 + per-group z3 max/min.
// Group (32 samples) completes every 2 phases. Max/min order-independent.
// ---------------------------------------------------------------------------
template<bool RECOMP>
__global__ __launch_bounds__(256) void conv2s_kernel(
        const float* __restrict__ xyz, const float* __restrict__ new_xyz,
        const int* __restrict__ idx, const float* __restrict__ P1,
        const float* __restrict__ w0, const float* __restrict__ b0,
        const float* __restrict__ stats1,
        const float* __restrict__ g0, const float* __restrict__ be0,
        const float* __restrict__ w1, const float* __restrict__ b1,
        const __hip_bfloat16* __restrict__ Z2,
        const float* __restrict__ stats2,
        const float* __restrict__ g1, const float* __restrict__ be1,
        const float* __restrict__ w2, const float* __restrict__ b2,
        float* __restrict__ stats_out,
        float* __restrict__ Z3max, float* __restrict__ Z3min) {
    const int tid = threadIdx.x;
    const int ch = tid & 63,  pg = tid >> 6;
    const int c2 = tid & 127, p2 = tid >> 7;

    __shared__ float w2ld[128 * 65];
    __shared__ float w1sm[RECOMP ? 64 * 65 : 1];
    __shared__ float inb1[RECOMP ? 16 : 1][68];
    __shared__ float inb2[16][68];
    __shared__ float dls[RECOMP ? 16 : 1][4];
    __shared__ int   iidx[RECOMP ? 16 : 1];
    __shared__ float red[512];
    __shared__ float pmax[2][128];
    __shared__ float pmin[2][128];

    for (int t = tid; t < 128 * 64; t += 256)
        w2ld[(t >> 6) * 65 + (t & 63)] = w2[t];
    if (RECOMP)
        for (int t = tid; t < 64 * 64; t += 256)
            w1sm[(t >> 6) * 65 + (t & 63)] = w1[t];
    __syncthreads();
    float wreg[64];
#pragma unroll
    for (int ic = 0; ic < 64; ++ic) wreg[ic] = w2ld[c2 * 65 + ic];

    float wx0 = 0.f, wx1 = 0.f, wx2 = 0.f, bb0 = 0.f, sc0 = 0.f, sh0 = 0.f, bb1 = 0.f;
    if (RECOMP) {
        wx0 = w0[ch * 67 + 0]; wx1 = w0[ch * 67 + 1]; wx2 = w0[ch * 67 + 2];
        bb0 = b0[ch];
        const float mn = stats1[ch] * INV_NTOT;
        const float vr = stats1[64 + ch] * INV_NTOT - mn * mn;
        sc0 = g0[ch] * rsqrtf(vr + BN_EPS);
        sh0 = be0[ch] - mn * sc0;
        bb1 = b1[ch];
    }
    float sc1, sh1;
    {
        const float mn = stats2[ch] * INV_NTOT;
        const float vr = stats2[64 + ch] * INV_NTOT - mn * mn;
        sc1 = g1[ch] * rsqrtf(vr + BN_EPS);
        sh1 = be1[ch] - mn * sc1;
    }
    const float bb2 = b2[c2];
    float sl = 0.f, sq = 0.f, mx = -FLT_MAX, mnv = FLT_MAX;

    const int base = blockIdx.x * 256;
    for (int t = 0; t < 16; ++t) {
        const int p0 = base + t * 16;
        if (RECOMP) {
            if (tid < 48) {
                const int pos = tid / 3, c = tid - pos * 3;
                const int p = p0 + pos;
                const int bm = p >> 5, b = bm >> 10;
                const int i = idx[p];
                dls[pos][c] = xyz[(((size_t)(b << 12)) + i) * 3 + c]
                            - new_xyz[(size_t)bm * 3 + c];
            } else if (tid < 64) {
                iidx[tid - 48] = idx[p0 + tid - 48];
            }
            __syncthreads();
#pragma unroll
            for (int k = 0; k < 4; ++k) {
                const int pos = pg + k * 4;
                const int p = p0 + pos;
                const int bm = p >> 5, b = bm >> 10;
                const int i = iidx[pos];
                const float z0 = z0_calc(P1[(((size_t)(b << 12)) + i) * 64 + ch], bb0,
                                         wx0, wx1, wx2, dls[pos][0], dls[pos][1], dls[pos][2]);
                inb1[pos][ch] = fmaxf(fmaf(z0, sc0, sh0), 0.f);
            }
            __syncthreads();
#pragma unroll
            for (int k = 0; k < 4; ++k) {
                const int pos = pg + k * 4;
                const float4* row1 = (const float4*)&inb1[pos][0];
                float z1 = bb1;
#pragma unroll
                for (int ic4 = 0; ic4 < 16; ++ic4) {
                    const float4 v = row1[ic4];
                    z1 = fmaf(w1sm[ch * 65 + 4 * ic4 + 0], v.x, z1);
                    z1 = fmaf(w1sm[ch * 65 + 4 * ic4 + 1], v.y, z1);
                    z1 = fmaf(w1sm[ch * 65 + 4 * ic4 + 2], v.z, z1);
                    z1 = fmaf(w1sm[ch * 65 + 4 * ic4 + 3], v.w, z1);
                }
                inb2[pos][ch] = fmaxf(fmaf(z1, sc1, sh1), 0.f);
            }
        } else {
#pragma unroll
            for (int k = 0; k < 4; ++k) {
                const int pos = pg + k * 4;
                const float z1 = __bfloat162float(Z2[(size_t)(p0 + pos) * 64 + ch]);
                inb2[pos][ch] = fmaxf(fmaf(z1, sc1, sh1), 0.f);
            }
        }
        __syncthreads();

#pragma unroll
        for (int j = 0; j < 8; ++j) {
            const int pos = p2 * 8 + j;
            const float4* row2 = (const float4*)&inb2[pos][0];
            float z2 = bb2;
#pragma unroll
            for (int ic4 = 0; ic4 < 16; ++ic4) {
                const float4 v = row2[ic4];
                z2 = fmaf(wreg[4 * ic4 + 0], v.x, z2);
                z2 = fmaf(wreg[4 * ic4 + 1], v.y, z2);
                z2 = fmaf(wreg[4 * ic4 + 2], v.z, z2);
                z2 = fmaf(wreg[4 * ic4 + 3], v.w, z2);
            }
            sl += z2; sq += z2 * z2;
            mx = fmaxf(mx, z2); mnv = fminf(mnv, z2);
        }
        if (t & 1) {                        // 32-sample group complete
            pmax[p2][c2] = mx; pmin[p2][c2] = mnv;
            __syncthreads();
            if (p2 == 0) {
                const int bm = (base >> 5) + (t >> 1);
                Z3max[(size_t)bm * 128 + c2] = fmaxf(pmax[0][c2], pmax[1][c2]);
                Z3min[(size_t)bm * 128 + c2] = fminf(pmin[0][c2], pmin[1][c2]);
            }
            mx = -FLT_MAX; mnv = FLT_MAX;
        }
        __syncthreads();
    }

    red[tid] = sl; red[256 + tid] = sq;
    __syncthreads();
    if (tid < 128) {
        atomicAdd(&stats_out[tid],       red[tid] + red[128 + tid]);
        atomicAdd(&stats_out[128 + tid], red[256 + tid] + red[256 + 128 + tid]);
    }
}

// ---------------------------------------------------------------------------
// K7: epilogue — BN2+ReLU on the selected z3 extreme, transposed write.
// ---------------------------------------------------------------------------
__global__ __launch_bounds__(256) void pool_mm_kernel(
        const float* __restrict__ Z3max, const float* __restrict__ Z3min,
        const float* __restrict__ stats,
        const float* __restrict__ g, const float* __restrict__ beta,
        float* __restrict__ outNP) {
    const int tid = threadIdx.x;
    const int mtile = blockIdx.x;    // 0..31
    const int b = blockIdx.y;        // 0..15
    const int ch = tid & 127, mh = tid >> 7;

    const float mean  = stats[ch] * INV_NTOT;
    const float var   = stats[128 + ch] * INV_NTOT - mean * mean;
    const float scale = g[ch] * rsqrtf(var + BN_EPS);
    const float shift = beta[ch] - mean * scale;

    __shared__ float pool[32][129];

    for (int pass = 0; pass < 16; ++pass) {
        const int ml = pass * 2 + mh;
        const size_t bm = (size_t)b * NPOINT + mtile * 32 + ml;
        const float zx = Z3max[bm * 128 + ch];
        const float zn = Z3min[bm * 128 + ch];
        const float zsel = (scale >= 0.f) ? zx : zn;
        pool[ml][ch] = fmaxf(fmaf(zsel, scale, shift), 0.f);
    }
    __syncthreads();

#pragma unroll
    for (int r = 0; r < 16; ++r) {
        const int o  = r * 256 + tid;
        const int ml = o & 31;
        const int c2 = o >> 5;
        outNP[((size_t)b * 128 + c2) * NPOINT + mtile * 32 + ml] = pool[ml][c2];
    }
}

// ---------------------------------------------------------------------------
// Legacy tier-C fallback (conv2 double pass) — unchanged.
// ---------------------------------------------------------------------------
template<bool RECOMP, bool FINAL>
__global__ __launch_bounds__(256) void conv2_kernel(
        const float* __restrict__ xyz, const float* __restrict__ new_xyz,
        const int* __restrict__ idx, const float* __restrict__ P1,
        const float* __restrict__ w0, const float* __restrict__ b0,
        const float* __restrict__ stats1,
        const float* __restrict__ g0, const float* __restrict__ be0,
        const float* __restrict__ w1, const float* __restrict__ b1,
        const __hip_bfloat16* __restrict__ Z2,
        const float* __restrict__ stats2,
        const float* __restrict__ g1, const float* __restrict__ be1,
        const float* __restrict__ w2, const float* __restrict__ b2,
        const float* __restrict__ stats3,
        const float* __restrict__ g2, const float* __restrict__ be2,
        float* __restrict__ stats_out, float* __restrict__ outNP) {
    const int tid = threadIdx.x;
    const int ch = tid & 63,  pl = tid >> 6;
    const int c2 = tid & 127, p2 = tid >> 7;

    __shared__ float w2sm[128 * 65];
    __shared__ float w1sm[RECOMP ? 64 * 65 : 1];
    __shared__ float inb1[RECOMP ? 4 : 1][65];
    __shared__ float inb2[4][65];
    __shared__ float dls[4][4];
    __shared__ float red[FINAL ? 1 : 512];
    __shared__ float pmax[FINAL ? 2 : 1][128];
    __shared__ float poolbuf[FINAL ? 8 : 1][129];

    for (int t = tid; t < 128 * 64; t += 256)
        w2sm[(t >> 6) * 65 + (t & 63)] = w2[t];
    if (RECOMP)
        for (int t = tid; t < 64 * 64; t += 256)
            w1sm[(t >> 6) * 65 + (t & 63)] = w1[t];

    float wx0 = 0.f, wx1 = 0.f, wx2 = 0.f, bb0 = 0.f, sc0 = 0.f, sh0 = 0.f, bb1 = 0.f;
    if (RECOMP) {
        wx0 = w0[ch * 67 + 0]; wx1 = w0[ch * 67 + 1]; wx2 = w0[ch * 67 + 2];
        bb0 = b0[ch];
        const float mn = stats1[ch] * INV_NTOT;
        const float vr = stats1[64 + ch] * INV_NTOT - mn * mn;
        sc0 = g0[ch] * rsqrtf(vr + BN_EPS);
        sh0 = be0[ch] - mn * sc0;
        bb1 = b1[ch];
    }
    float sc1, sh1;
    {
        const float mn = stats2[ch] * INV_NTOT;
        const float vr = stats2[64 + ch] * INV_NTOT - mn * mn;
        sc1 = g1[ch] * rsqrtf(vr + BN_EPS);
        sh1 = be1[ch] - mn * sc1;
    }
    const float bb2 = b2[c2];
    float sc2 = 0.f, sh2 = 0.f;
    if (FINAL) {
        const float mn = stats3[c2] * INV_NTOT;
        const float vr = stats3[128 + c2] * INV_NTOT - mn * mn;
        sc2 = g2[c2] * rsqrtf(vr + BN_EPS);
        sh2 = be2[c2] - mn * sc2;
    }
    float sl = 0.f, sq = 0.f, mx = -FLT_MAX;
    __syncthreads();

    const int base = blockIdx.x * 256;
    for (int t = 0; t < 64; ++t) {
        const int p = base + t * 4 + pl;
        if (RECOMP) {
            const int i = idx[p];
            const int bm = p >> 5;
            const int b  = bm >> 10;
            if (ch < 3)
                dls[pl][ch] = xyz[(((size_t)(b << 12)) + i) * 3 + ch]
                            - new_xyz[(size_t)bm * 3 + ch];
            __syncthreads();
            const float z0 = z0_calc(P1[(((size_t)(b << 12)) + i) * 64 + ch], bb0,
                                     wx0, wx1, wx2, dls[pl][0], dls[pl][1], dls[pl][2]);
            inb1[pl][ch] = fmaxf(fmaf(z0, sc0, sh0), 0.f);
            __syncthreads();
            float z1 = bb1;
#pragma unroll
            for (int ic = 0; ic < 64; ++ic)
                z1 = fmaf(w1sm[ch * 65 + ic], inb1[pl][ic], z1);
            inb2[pl][ch] = fmaxf(fmaf(z1, sc1, sh1), 0.f);
        } else {
            const float z1 = __bfloat162float(Z2[(size_t)p * 64 + ch]);
            inb2[pl][ch] = fmaxf(fmaf(z1, sc1, sh1), 0.f);
        }
        __syncthreads();

#pragma unroll
        for (int q = 0; q < 2; ++q) {
            const int pr = q * 2 + p2;
            float z2 = bb2;
#pragma unroll
            for (int ic = 0; ic < 64; ++ic)
                z2 = fmaf(w2sm[c2 * 65 + ic], inb2[pr][ic], z2);
            if (FINAL) {
                mx = fmaxf(mx, fmaxf(fmaf(z2, sc2, sh2), 0.f));
            } else {
                sl += z2; sq += z2 * z2;
            }
        }
        if (FINAL && ((t & 7) == 7)) {
            pmax[p2][c2] = mx;
            __syncthreads();
            if (p2 == 0)
                poolbuf[t >> 3][c2] = fmaxf(pmax[0][c2], pmax[1][c2]);
            mx = -FLT_MAX;
        }
        __syncthreads();
    }

    if (FINAL) {
        const int b  = base >> 15;
        const int m0 = (base >> 5) & 1023;
#pragma unroll
        for (int r = 0; r < 4; ++r) {
            const int o   = r * 256 + tid;
            const int row = o >> 3;
            const int gg  = o & 7;
            outNP[((size_t)(b * 128 + row)) * 1024 + m0 + gg] = poolbuf[gg][row];
        }
    } else {
        red[tid] = sl; red[256 + tid] = sq;
        __syncthreads();
        if (tid < 128) {
            atomicAdd(&stats_out[tid],       red[tid] + red[128 + tid]);
            atomicAdd(&stats_out[128 + tid], red[256 + tid] + red[256 + 128 + tid]);
        }
    }
}

// ---------------------------------------------------------------------------
extern "C" void kernel_launch(void* const* d_in, const int* in_sizes, int n_in,
                              void* d_out, int out_size, void* d_ws, size_t ws_size,
                              hipStream_t stream) {
    const float* xyz    = (const float*)d_in[0];
    const float* points = (const float*)d_in[1];
    const float* w0  = (const float*)d_in[2];
    const float* b0  = (const float*)d_in[3];
    const float* g0  = (const float*)d_in[4];
    const float* be0 = (const float*)d_in[5];
    const float* w1  = (const float*)d_in[6];
    const float* b1  = (const float*)d_in[7];
    const float* g1  = (const float*)d_in[8];
    const float* be1 = (const float*)d_in[9];
    const float* w2  = (const float*)d_in[10];
    const float* b2  = (const float*)d_in[11];
    const float* g2  = (const float*)d_in[12];
    const float* be2 = (const float*)d_in[13];

    float* out        = (float*)d_out;
    float* new_xyz    = out;
    float* new_points = out + (size_t)BATCH * NPOINT * 3;

    // ws: idx 2MB | stats 4KB | P1 16MB | Z3max 8MB | Z3min 8MB | Z2 64MB
    char* ws = (char*)d_ws;
    int*   idx   = (int*)ws;
    float* stats = (float*)(ws + (size_t)(2u << 20));
    float* P1    = (float*)(ws + (size_t)(2u << 20) + 4096);
    const size_t offMM = (size_t)(2u << 20) + 4096 + (size_t)BATCH * NPTS * 64 * 4;
    float* Z3max = (float*)(ws + offMM);
    float* Z3min = Z3max + (size_t)BATCH * NPOINT * 128;
    const size_t offZ2 = offMM + (size_t)BATCH * NPOINT * 128 * 4 * 2;
    __hip_bfloat16* Z2 = (__hip_bfloat16*)(ws + offZ2);

    const bool tierA = ws_size >= offZ2 + (size_t)NTOT * 64 * 2;  // ~98 MB
    const bool tierB = ws_size >= offZ2;                          // ~34 MB

    float* stats1 = stats;
    float* stats2 = stats + 128;
    float* stats3 = stats + 256;

    init_stats_kernel<<<1, 512, 0, stream>>>(stats);
    p1_kernel<<<BATCH * NPTS / 256, 256, 0, stream>>>(points, w0, P1);
    fps_kernel<<<BATCH, 512, 0, stream>>>(xyz, new_xyz);
    knn_kernel<<<dim3(NPOINT, BATCH), 256, 0, stream>>>(xyz, new_xyz, idx);
    stats0_kernel<<<NTOT / 256, 256, 0, stream>>>(xyz, new_xyz, idx, P1,
                                                  w0, b0, stats1);
    if (tierA) {
        conv1_kernel<true><<<NTOT / 256, 256, 0, stream>>>(
            xyz, new_xyz, idx, P1, w0, b0, stats1, g0, be0, w1, b1, Z2, stats2);
        conv2s_kernel<false><<<NTOT / 256, 256, 0, stream>>>(
            xyz, new_xyz, idx, P1, w0, b0, stats1, g0, be0, w1, b1, Z2,
            stats2, g1, be1, w2, b2, stats3, Z3max, Z3min);
        pool_mm_kernel<<<dim3(32, BATCH), 256, 0, stream>>>(
            Z3max, Z3min, stats3, g2, be2, new_points);
    } else if (tierB) {
        conv1_kernel<false><<<NTOT / 256, 256, 0, stream>>>(
            xyz, new_xyz, idx, P1, w0, b0, stats1, g0, be0, w1, b1, Z2, stats2);
        conv2s_kernel<true><<<NTOT / 256, 256, 0, stream>>>(
            xyz, new_xyz, idx, P1, w0, b0, stats1, g0, be0, w1, b1, Z2,
            stats2, g1, be1, w2, b2, stats3, Z3max, Z3min);
        pool_mm_kernel<<<dim3(32, BATCH), 256, 0, stream>>>(
            Z3max, Z3min, stats3, g2, be2, new_points);
    } else {
        conv1_kernel<false><<<NTOT / 256, 256, 0, stream>>>(
            xyz, new_xyz, idx, P1, w0, b0, stats1, g0, be0, w1, b1, Z2, stats2);
        conv2_kernel<true, false><<<NTOT / 256, 256, 0, stream>>>(
            xyz, new_xyz, idx, P1, w0, b0, stats1, g0, be0, w1, b1, Z2,
            stats2, g1, be1, w2, b2, stats3, g2, be2, stats3, new_points);
        conv2_kernel<true, true><<<NTOT / 256, 256, 0, stream>>>(
            xyz, new_xyz, idx, P1, w0, b0, stats1, g0, be0, w1, b1, Z2,
            stats2, g1, be1, w2, b2, stats3, g2, be2, stats3, new_points);
    }
}

// Round 11
// 1688.755 us; speedup vs baseline: 1.6678x; 1.1758x over previous
//
#include <hip/hip_runtime.h>
#include <hip/hip_bf16.h>
#include <float.h>

#define NPTS    4096
#define NPOINT  1024
#define NSAMPLE 32
#define BATCH   16
#define NTOT    (BATCH * NPOINT * NSAMPLE)   // 524288 gathered pairs
#define INV_NTOT (1.0f / 524288.0f)
#define BN_EPS  1e-5f
#define S1REP   32                            // stats1 atomic replicas

// ---------------------------------------------------------------------------
// DPP wave-64 reduction helpers (pure VALU — no LDS-pipe bpermute/swizzle).
// ---------------------------------------------------------------------------
template<int CTRL, int OLD>
__device__ __forceinline__ unsigned long long dpp_move_u64(unsigned long long v) {
    const int lo = __builtin_amdgcn_update_dpp(OLD, (int)(unsigned)v,        CTRL, 0xF, 0xF, false);
    const int hi = __builtin_amdgcn_update_dpp(OLD, (int)(unsigned)(v >> 32), CTRL, 0xF, 0xF, false);
    return ((unsigned long long)(unsigned)hi << 32) | (unsigned)lo;
}

__device__ __forceinline__ unsigned long long dpp_max64_to_lane63(unsigned long long v) {
    unsigned long long o;
    o = dpp_move_u64<0x111, 0>(v); v = o > v ? o : v;
    o = dpp_move_u64<0x112, 0>(v); v = o > v ? o : v;
    o = dpp_move_u64<0x114, 0>(v); v = o > v ? o : v;
    o = dpp_move_u64<0x118, 0>(v); v = o > v ? o : v;
    o = dpp_move_u64<0x142, 0>(v); v = o > v ? o : v;
    o = dpp_move_u64<0x143, 0>(v); v = o > v ? o : v;
    return v;
}

__device__ __forceinline__ unsigned long long dpp_min64_to_lane63(unsigned long long v) {
    unsigned long long o;
    o = dpp_move_u64<0x111, -1>(v); v = o < v ? o : v;
    o = dpp_move_u64<0x112, -1>(v); v = o < v ? o : v;
    o = dpp_move_u64<0x114, -1>(v); v = o < v ? o : v;
    o = dpp_move_u64<0x118, -1>(v); v = o < v ? o : v;
    o = dpp_move_u64<0x142, -1>(v); v = o < v ? o : v;
    o = dpp_move_u64<0x143, -1>(v); v = o < v ? o : v;
    return v;
}

__device__ __forceinline__ unsigned long long readlane63_u64(unsigned long long v) {
    const unsigned lo = (unsigned)__builtin_amdgcn_readlane((int)(unsigned)v, 63);
    const unsigned hi = (unsigned)__builtin_amdgcn_readlane((int)(unsigned)(v >> 32), 63);
    return ((unsigned long long)hi << 32) | lo;
}

// ---------------------------------------------------------------------------
// K0: zero 4608 stats floats (32 replicas x 128 + stats2 128 + stats3 256).
// ---------------------------------------------------------------------------
__global__ void init_stats_kernel(float* __restrict__ stats) {
#pragma unroll
    for (int t = 0; t < 9; ++t)
        stats[t * 512 + threadIdx.x] = 0.0f;
}

// ---------------------------------------------------------------------------
// K1: FPS — 256 threads (4 waves), 16 pts/thread. Same per-point op order /
// tie-breaks as the verified 512-thread version (k ascending == global index
// ascending; strictly-greater keeps first). Merge: 4 slots (was 8), cheaper
// barrier. key = bits(dist)<<32 | (4095-i).
// ---------------------------------------------------------------------------
__global__ __launch_bounds__(256) void fps_kernel(const float* __restrict__ xyz,
                                                  float* __restrict__ new_xyz) {
#pragma clang fp contract(off)
    const int b = blockIdx.x, tid = threadIdx.x;
    const int lane = tid & 63, wave = tid >> 6;
    const float* X = xyz + (size_t)b * NPTS * 3;
    float* outC = new_xyz + (size_t)b * NPOINT * 3;

    __shared__ float xs[NPTS], ys[NPTS], zs[NPTS];
    __shared__ unsigned long long wred[2][4];

    float px[16], py[16], pz[16], dd[16];
    unsigned idneg[16];
#pragma unroll
    for (int k = 0; k < 16; ++k) {
        const int i = tid + k * 256;
        px[k] = X[i * 3 + 0]; py[k] = X[i * 3 + 1]; pz[k] = X[i * 3 + 2];
        dd[k] = 1e10f;
        idneg[k] = (unsigned)(4095 - i);
        xs[i] = px[k]; ys[i] = py[k]; zs[i] = pz[k];
    }
    __syncthreads();

    int far = 0;
    for (int it = 0; it < NPOINT; ++it) {
        const float cx = xs[far], cy = ys[far], cz = zs[far];
        if (tid == 0) {
            outC[it * 3 + 0] = cx; outC[it * 3 + 1] = cy; outC[it * 3 + 2] = cz;
        }
        float bv = -1.0f; unsigned biNeg = 0;
#pragma unroll
        for (int k = 0; k < 16; ++k) {
            const float dx = px[k] - cx, dy = py[k] - cy, dz = pz[k] - cz;
            const float dist = (dx * dx + dy * dy) + dz * dz;
            const float nd = fminf(dd[k], dist);
            dd[k] = nd;
            const bool gt = nd > bv;
            bv = gt ? nd : bv;
            biNeg = gt ? idneg[k] : biNeg;
        }
        unsigned long long best =
            ((unsigned long long)__float_as_uint(bv) << 32) | biNeg;
        best = dpp_max64_to_lane63(best);
        if (lane == 63) wred[it & 1][wave] = best;
        __syncthreads();
        unsigned long long g = wred[it & 1][0];
#pragma unroll
        for (int w = 1; w < 4; ++w) {
            const unsigned long long o = wred[it & 1][w];
            g = o > g ? o : g;
        }
        far = 4095 - (int)(g & 0xFFFFFFFFull);
    }
}

// ---------------------------------------------------------------------------
// K2: k-nearest + FUSED layer-0 stats. After selecting this centroid's 32
// neighbors, the block computes z0 (pre-BN layer-0) for 32 pos x 64 ch and
// reduces into one of 32 stats1 replicas (atomic-contention spread).
// z0 arithmetic identical to the conv kernels' recompute -> bit-identical.
// ---------------------------------------------------------------------------
__global__ __launch_bounds__(256) void knn_kernel(const float* __restrict__ xyz,
                                                  const float* __restrict__ new_xyz,
                                                  const float* __restrict__ P1,
                                                  const float* __restrict__ w0,
                                                  const float* __restrict__ b0,
                                                  int* __restrict__ idx,
                                                  float* __restrict__ stats1) {
#pragma clang fp contract(off)
    const int m = blockIdx.x, b = blockIdx.y;
    const int tid = threadIdx.x;
    const int lane = tid & 63, wave = tid >> 6;
    const float* X = xyz + (size_t)b * NPTS * 3;
    const float* c = new_xyz + ((size_t)b * NPOINT + m) * 3;
    const float cx = c[0], cy = c[1], cz = c[2];
    const float sqc = (cx * cx + cy * cy) + cz * cz;

    unsigned long long key[16];
#pragma unroll
    for (int k = 0; k < 16; ++k) {
        const int i = wave * 1024 + k * 64 + lane;
        const float x = X[i * 3 + 0];
        const float y = X[i * 3 + 1];
        const float z = X[i * 3 + 2];
        const float sqi = (x * x + y * y) + z * z;
        const float dot = (cx * x + cy * y) + cz * z;
        const float d2 = (sqc + sqi) - 2.0f * dot;
        const unsigned u = __float_as_uint(d2);
        const unsigned s = u ^ (unsigned)(((int)u >> 31) | 0x80000000);
        key[k] = ((unsigned long long)s << 32) | (unsigned)i;
    }

    __shared__ unsigned long long wk[128];
    __shared__ int widx[32];
    __shared__ float red[512];

    for (int j = 0; j < NSAMPLE; ++j) {
        unsigned long long best = key[0];
#pragma unroll
        for (int k = 1; k < 16; ++k) best = key[k] < best ? key[k] : best;
        best = dpp_min64_to_lane63(best);
        const unsigned long long bestAll = readlane63_u64(best);
        if (lane == 0) wk[wave * 32 + j] = bestAll;
#pragma unroll
        for (int k = 0; k < 16; ++k)
            key[k] = (key[k] == bestAll) ? ~0ull : key[k];
    }
    __syncthreads();

    if (wave == 0) {
        int* out = idx + ((size_t)b * NPOINT + m) * NSAMPLE;
        unsigned long long a = wk[lane], bb = wk[64 + lane];
        for (int j = 0; j < NSAMPLE; ++j) {
            unsigned long long best = a < bb ? a : bb;
            best = dpp_min64_to_lane63(best);
            const unsigned long long bestAll = readlane63_u64(best);
            if (lane == 0) {
                const int gi = (int)(bestAll & 0xFFFFFFFFull);
                out[j] = gi;
                widx[j] = gi;
            }
            a  = (a  == bestAll) ? ~0ull : a;
            bb = (bb == bestAll) ? ~0ull : bb;
        }
    }
    __syncthreads();

    // ---- fused layer-0 stats over this block's 32 gathered positions ----
    const int ch = tid & 63, grp = tid >> 6;
    const float wx0 = w0[ch * 67 + 0], wx1 = w0[ch * 67 + 1], wx2 = w0[ch * 67 + 2];
    const float bb0 = b0[ch];
    float sl = 0.f, sq = 0.f;
#pragma unroll
    for (int j = 0; j < 8; ++j) {
        const int i = widx[grp * 8 + j];
        const float dx = X[i * 3 + 0] - cx;
        const float dy = X[i * 3 + 1] - cy;
        const float dz = X[i * 3 + 2] - cz;
        const float p1v = P1[(((size_t)(b << 12)) + i) * 64 + ch];
        const float z = fmaf(wx2, dz, fmaf(wx1, dy, fmaf(wx0, dx, p1v + bb0)));
        sl += z; sq += z * z;
    }
    red[tid] = sl; red[256 + tid] = sq;
    __syncthreads();
    if (grp == 0) {
        float* rep = stats1 + (size_t)(m & (S1REP - 1)) * 128;
        atomicAdd(&rep[ch],
                  red[ch] + red[64 + ch] + red[128 + ch] + red[192 + ch]);
        atomicAdd(&rep[64 + ch],
                  red[256 + ch] + red[256 + 64 + ch] + red[256 + 128 + ch] + red[256 + 192 + ch]);
    }
}

// ---------------------------------------------------------------------------
// K3: P1 = points @ w0[:,3:]^T — 16-point phases, register weights.
// ---------------------------------------------------------------------------
__global__ __launch_bounds__(256) void p1_kernel(const float* __restrict__ points,
                                                 const float* __restrict__ w0,
                                                 float* __restrict__ P1) {
    const int tid = threadIdx.x;
    const int ch = tid & 63, pg = tid >> 6;
    __shared__ float wld[64 * 65];
    __shared__ float inb[16][68];
    for (int t = tid; t < 64 * 64; t += 256)
        wld[(t >> 6) * 65 + (t & 63)] = w0[(t >> 6) * 67 + 3 + (t & 63)];
    __syncthreads();
    float wreg[64];
#pragma unroll
    for (int ic = 0; ic < 64; ++ic) wreg[ic] = wld[ch * 65 + ic];

    const int base = blockIdx.x * 256;
    for (int t = 0; t < 16; ++t) {
        const int q0 = base + t * 16;
#pragma unroll
        for (int k = 0; k < 4; ++k) {
            const int pos = pg + k * 4;
            inb[pos][ch] = points[(size_t)(q0 + pos) * 64 + ch];
        }
        __syncthreads();
#pragma unroll
        for (int j = 0; j < 4; ++j) {
            const int pos = pg * 4 + j;
            const float4* row = (const float4*)&inb[pos][0];
            float acc = 0.f;
#pragma unroll
            for (int ic4 = 0; ic4 < 16; ++ic4) {
                const float4 v = row[ic4];
                acc = fmaf(wreg[4 * ic4 + 0], v.x, acc);
                acc = fmaf(wreg[4 * ic4 + 1], v.y, acc);
                acc = fmaf(wreg[4 * ic4 + 2], v.z, acc);
                acc = fmaf(wreg[4 * ic4 + 3], v.w, acc);
            }
            P1[(size_t)(q0 + pos) * 64 + ch] = acc;
        }
        __syncthreads();
    }
}

__device__ __forceinline__ float z0_calc(float p1v, float bb, float wx0, float wx1,
                                         float wx2, float dx, float dy, float dz) {
    return fmaf(wx2, dz, fmaf(wx1, dy, fmaf(wx0, dx, p1v + bb)));
}

// sum the 32 stats1 replicas for channel ch -> (sum, sumsq)
__device__ __forceinline__ void stats1_sum(const float* __restrict__ stats1,
                                           int ch, float& s, float& q) {
    s = 0.f; q = 0.f;
#pragma unroll
    for (int r = 0; r < S1REP; ++r) {
        s += stats1[r * 128 + ch];
        q += stats1[r * 128 + 64 + ch];
    }
}

// ---------------------------------------------------------------------------
// K5: conv1 — 16-position phases, register weights (round-10 structure).
// ---------------------------------------------------------------------------
template<bool STORE>
__global__ __launch_bounds__(256) void conv1_kernel(
        const float* __restrict__ xyz, const float* __restrict__ new_xyz,
        const int* __restrict__ idx, const float* __restrict__ P1,
        const float* __restrict__ w0, const float* __restrict__ b0,
        const float* __restrict__ stats1,
        const float* __restrict__ g0, const float* __restrict__ be0,
        const float* __restrict__ w1, const float* __restrict__ b1,
        __hip_bfloat16* __restrict__ Z2, float* __restrict__ stats_out) {
    const int tid = threadIdx.x;
    const int ch = tid & 63, pg = tid >> 6;
    __shared__ float w1ld[64 * 65];
    __shared__ float inb1[16][68];
    __shared__ float dls[16][4];
    __shared__ int   iidx[16];
    __shared__ float red[512];
    for (int t = tid; t < 64 * 64; t += 256)
        w1ld[(t >> 6) * 65 + (t & 63)] = w1[t];
    __syncthreads();
    float wreg[64];
#pragma unroll
    for (int ic = 0; ic < 64; ++ic) wreg[ic] = w1ld[ch * 65 + ic];

    const float wx0 = w0[ch * 67 + 0], wx1 = w0[ch * 67 + 1], wx2 = w0[ch * 67 + 2];
    const float bb0 = b0[ch];
    float s1, q1;
    stats1_sum(stats1, ch, s1, q1);
    const float mn = s1 * INV_NTOT;
    const float vr = q1 * INV_NTOT - mn * mn;
    const float sc0 = g0[ch] * rsqrtf(vr + BN_EPS);
    const float sh0 = be0[ch] - mn * sc0;
    const float bb1 = b1[ch];
    float sl = 0.f, sq = 0.f;

    const int base = blockIdx.x * 256;
    for (int t = 0; t < 16; ++t) {
        const int p0 = base + t * 16;
        if (tid < 48) {
            const int pos = tid / 3, c = tid - pos * 3;
            const int p = p0 + pos;
            const int bm = p >> 5, b = bm >> 10;
            const int i = idx[p];
            dls[pos][c] = xyz[(((size_t)(b << 12)) + i) * 3 + c]
                        - new_xyz[(size_t)bm * 3 + c];
        } else if (tid < 64) {
            iidx[tid - 48] = idx[p0 + tid - 48];
        }
        __syncthreads();
#pragma unroll
        for (int k = 0; k < 4; ++k) {
            const int pos = pg + k * 4;
            const int p = p0 + pos;
            const int bm = p >> 5, b = bm >> 10;
            const int i = iidx[pos];
            const float z0 = z0_calc(P1[(((size_t)(b << 12)) + i) * 64 + ch], bb0,
                                     wx0, wx1, wx2, dls[pos][0], dls[pos][1], dls[pos][2]);
            inb1[pos][ch] = fmaxf(fmaf(z0, sc0, sh0), 0.f);
        }
        __syncthreads();
#pragma unroll
        for (int j = 0; j < 4; ++j) {
            const int pos = pg * 4 + j;
            const float4* row = (const float4*)&inb1[pos][0];
            float z1 = bb1;
#pragma unroll
            for (int ic4 = 0; ic4 < 16; ++ic4) {
                const float4 v = row[ic4];
                z1 = fmaf(wreg[4 * ic4 + 0], v.x, z1);
                z1 = fmaf(wreg[4 * ic4 + 1], v.y, z1);
                z1 = fmaf(wreg[4 * ic4 + 2], v.z, z1);
                z1 = fmaf(wreg[4 * ic4 + 3], v.w, z1);
            }
            if (STORE) Z2[(size_t)(p0 + pos) * 64 + ch] = __float2bfloat16(z1);
            sl += z1; sq += z1 * z1;
        }
        __syncthreads();
    }
    red[tid] = sl; red[256 + tid] = sq;
    __syncthreads();
    if (pg == 0) {
        atomicAdd(&stats_out[ch],
                  red[ch] + red[64 + ch] + red[128 + ch] + red[192 + ch]);
        atomicAdd(&stats_out[64 + ch],
                  red[256 + ch] + red[256 + 64 + ch] + red[256 + 128 + ch] + red[256 + 192 + ch]);
    }
}

// ---------------------------------------------------------------------------
// K6: conv2 single pass — 16-position phases; stats3 + per-group z3 max/min.
// ---------------------------------------------------------------------------
template<bool RECOMP>
__global__ __launch_bounds__(256) void conv2s_kernel(
        const float* __restrict__ xyz, const float* __restrict__ new_xyz,
        const int* __restrict__ idx, const float* __restrict__ P1,
        const float* __restrict__ w0, const float* __restrict__ b0,
        const float* __restrict__ stats1,
        const float* __restrict__ g0, const float* __restrict__ be0,
        const float* __restrict__ w1, const float* __restrict__ b1,
        const __hip_bfloat16* __restrict__ Z2,
        const float* __restrict__ stats2,
        const float* __restrict__ g1, const float* __restrict__ be1,
        const float* __restrict__ w2, const float* __restrict__ b2,
        float* __restrict__ stats_out,
        float* __restrict__ Z3max, float* __restrict__ Z3min) {
    const int tid = threadIdx.x;
    const int ch = tid & 63,  pg = tid >> 6;
    const int c2 = tid & 127, p2 = tid >> 7;

    __shared__ float w2ld[128 * 65];
    __shared__ float w1sm[RECOMP ? 64 * 65 : 1];
    __shared__ float inb1[RECOMP ? 16 : 1][68];
    __shared__ float inb2[16][68];
    __shared__ float dls[RECOMP ? 16 : 1][4];
    __shared__ int   iidx[RECOMP ? 16 : 1];
    __shared__ float red[512];
    __shared__ float pmax[2][128];
    __shared__ float pmin[2][128];

    for (int t = tid; t < 128 * 64; t += 256)
        w2ld[(t >> 6) * 65 + (t & 63)] = w2[t];
    if (RECOMP)
        for (int t = tid; t < 64 * 64; t += 256)
            w1sm[(t >> 6) * 65 + (t & 63)] = w1[t];
    __syncthreads();
    float wreg[64];
#pragma unroll
    for (int ic = 0; ic < 64; ++ic) wreg[ic] = w2ld[c2 * 65 + ic];

    float wx0 = 0.f, wx1 = 0.f, wx2 = 0.f, bb0 = 0.f, sc0 = 0.f, sh0 = 0.f, bb1 = 0.f;
    if (RECOMP) {
        wx0 = w0[ch * 67 + 0]; wx1 = w0[ch * 67 + 1]; wx2 = w0[ch * 67 + 2];
        bb0 = b0[ch];
        float s1, q1;
        stats1_sum(stats1, ch, s1, q1);
        const float mn = s1 * INV_NTOT;
        const float vr = q1 * INV_NTOT - mn * mn;
        sc0 = g0[ch] * rsqrtf(vr + BN_EPS);
        sh0 = be0[ch] - mn * sc0;
        bb1 = b1[ch];
    }
    float sc1, sh1;
    {
        const float mn = stats2[ch] * INV_NTOT;
        const float vr = stats2[64 + ch] * INV_NTOT - mn * mn;
        sc1 = g1[ch] * rsqrtf(vr + BN_EPS);
        sh1 = be1[ch] - mn * sc1;
    }
    const float bb2 = b2[c2];
    float sl = 0.f, sq = 0.f, mx = -FLT_MAX, mnv = FLT_MAX;

    const int base = blockIdx.x * 256;
    for (int t = 0; t < 16; ++t) {
        const int p0 = base + t * 16;
        if (RECOMP) {
            if (tid < 48) {
                const int pos = tid / 3, c = tid - pos * 3;
                const int p = p0 + pos;
                const int bm = p >> 5, b = bm >> 10;
                const int i = idx[p];
                dls[pos][c] = xyz[(((size_t)(b << 12)) + i) * 3 + c]
                            - new_xyz[(size_t)bm * 3 + c];
            } else if (tid < 64) {
                iidx[tid - 48] = idx[p0 + tid - 48];
            }
            __syncthreads();
#pragma unroll
            for (int k = 0; k < 4; ++k) {
                const int pos = pg + k * 4;
                const int p = p0 + pos;
                const int bm = p >> 5, b = bm >> 10;
                const int i = iidx[pos];
                const float z0 = z0_calc(P1[(((size_t)(b << 12)) + i) * 64 + ch], bb0,
                                         wx0, wx1, wx2, dls[pos][0], dls[pos][1], dls[pos][2]);
                inb1[pos][ch] = fmaxf(fmaf(z0, sc0, sh0), 0.f);
            }
            __syncthreads();
#pragma unroll
            for (int k = 0; k < 4; ++k) {
                const int pos = pg + k * 4;
                const float4* row1 = (const float4*)&inb1[pos][0];
                float z1 = bb1;
#pragma unroll
                for (int ic4 = 0; ic4 < 16; ++ic4) {
                    const float4 v = row1[ic4];
                    z1 = fmaf(w1sm[ch * 65 + 4 * ic4 + 0], v.x, z1);
                    z1 = fmaf(w1sm[ch * 65 + 4 * ic4 + 1], v.y, z1);
                    z1 = fmaf(w1sm[ch * 65 + 4 * ic4 + 2], v.z, z1);
                    z1 = fmaf(w1sm[ch * 65 + 4 * ic4 + 3], v.w, z1);
                }
                inb2[pos][ch] = fmaxf(fmaf(z1, sc1, sh1), 0.f);
            }
        } else {
#pragma unroll
            for (int k = 0; k < 4; ++k) {
                const int pos = pg + k * 4;
                const float z1 = __bfloat162float(Z2[(size_t)(p0 + pos) * 64 + ch]);
                inb2[pos][ch] = fmaxf(fmaf(z1, sc1, sh1), 0.f);
            }
        }
        __syncthreads();

#pragma unroll
        for (int j = 0; j < 8; ++j) {
            const int pos = p2 * 8 + j;
            const float4* row2 = (const float4*)&inb2[pos][0];
            float z2 = bb2;
#pragma unroll
            for (int ic4 = 0; ic4 < 16; ++ic4) {
                const float4 v = row2[ic4];
                z2 = fmaf(wreg[4 * ic4 + 0], v.x, z2);
                z2 = fmaf(wreg[4 * ic4 + 1], v.y, z2);
                z2 = fmaf(wreg[4 * ic4 + 2], v.z, z2);
                z2 = fmaf(wreg[4 * ic4 + 3], v.w, z2);
            }
            sl += z2; sq += z2 * z2;
            mx = fmaxf(mx, z2); mnv = fminf(mnv, z2);
        }
        if (t & 1) {                        // 32-sample group complete
            pmax[p2][c2] = mx; pmin[p2][c2] = mnv;
            __syncthreads();
            if (p2 == 0) {
                const int bm = (base >> 5) + (t >> 1);
                Z3max[(size_t)bm * 128 + c2] = fmaxf(pmax[0][c2], pmax[1][c2]);
                Z3min[(size_t)bm * 128 + c2] = fminf(pmin[0][c2], pmin[1][c2]);
            }
            mx = -FLT_MAX; mnv = FLT_MAX;
        }
        __syncthreads();
    }

    red[tid] = sl; red[256 + tid] = sq;
    __syncthreads();
    if (tid < 128) {
        atomicAdd(&stats_out[tid],       red[tid] + red[128 + tid]);
        atomicAdd(&stats_out[128 + tid], red[256 + tid] + red[256 + 128 + tid]);
    }
}

// ---------------------------------------------------------------------------
// K7: epilogue — BN2+ReLU on the selected z3 extreme, transposed write.
// ---------------------------------------------------------------------------
__global__ __launch_bounds__(256) void pool_mm_kernel(
        const float* __restrict__ Z3max, const float* __restrict__ Z3min,
        const float* __restrict__ stats,
        const float* __restrict__ g, const float* __restrict__ beta,
        float* __restrict__ outNP) {
    const int tid = threadIdx.x;
    const int mtile = blockIdx.x;    // 0..31
    const int b = blockIdx.y;        // 0..15
    const int ch = tid & 127, mh = tid >> 7;

    const float mean  = stats[ch] * INV_NTOT;
    const float var   = stats[128 + ch] * INV_NTOT - mean * mean;
    const float scale = g[ch] * rsqrtf(var + BN_EPS);
    const float shift = beta[ch] - mean * scale;

    __shared__ float pool[32][129];

    for (int pass = 0; pass < 16; ++pass) {
        const int ml = pass * 2 + mh;
        const size_t bm = (size_t)b * NPOINT + mtile * 32 + ml;
        const float zx = Z3max[bm * 128 + ch];
        const float zn = Z3min[bm * 128 + ch];
        const float zsel = (scale >= 0.f) ? zx : zn;
        pool[ml][ch] = fmaxf(fmaf(zsel, scale, shift), 0.f);
    }
    __syncthreads();

#pragma unroll
    for (int r = 0; r < 16; ++r) {
        const int o  = r * 256 + tid;
        const int ml = o & 31;
        const int c2 = o >> 5;
        outNP[((size_t)b * 128 + c2) * NPOINT + mtile * 32 + ml] = pool[ml][c2];
    }
}

// ---------------------------------------------------------------------------
// Legacy tier-C fallback (conv2 double pass) — stats1 via replica sum.
// ---------------------------------------------------------------------------
template<bool RECOMP, bool FINAL>
__global__ __launch_bounds__(256) void conv2_kernel(
        const float* __restrict__ xyz, const float* __restrict__ new_xyz,
        const int* __restrict__ idx, const float* __restrict__ P1,
        const float* __restrict__ w0, const float* __restrict__ b0,
        const float* __restrict__ stats1,
        const float* __restrict__ g0, const float* __restrict__ be0,
        const float* __restrict__ w1, const float* __restrict__ b1,
        const __hip_bfloat16* __restrict__ Z2,
        const float* __restrict__ stats2,
        const float* __restrict__ g1, const float* __restrict__ be1,
        const float* __restrict__ w2, const float* __restrict__ b2,
        const float* __restrict__ stats3,
        const float* __restrict__ g2, const float* __restrict__ be2,
        float* __restrict__ stats_out, float* __restrict__ outNP) {
    const int tid = threadIdx.x;
    const int ch = tid & 63,  pl = tid >> 6;
    const int c2 = tid & 127, p2 = tid >> 7;

    __shared__ float w2sm[128 * 65];
    __shared__ float w1sm[RECOMP ? 64 * 65 : 1];
    __shared__ float inb1[RECOMP ? 4 : 1][65];
    __shared__ float inb2[4][65];
    __shared__ float dls[4][4];
    __shared__ float red[FINAL ? 1 : 512];
    __shared__ float pmax[FINAL ? 2 : 1][128];
    __shared__ float poolbuf[FINAL ? 8 : 1][129];

    for (int t = tid; t < 128 * 64; t += 256)
        w2sm[(t >> 6) * 65 + (t & 63)] = w2[t];
    if (RECOMP)
        for (int t = tid; t < 64 * 64; t += 256)
            w1sm[(t >> 6) * 65 + (t & 63)] = w1[t];

    float wx0 = 0.f, wx1 = 0.f, wx2 = 0.f, bb0 = 0.f, sc0 = 0.f, sh0 = 0.f, bb1 = 0.f;
    if (RECOMP) {
        wx0 = w0[ch * 67 + 0]; wx1 = w0[ch * 67 + 1]; wx2 = w0[ch * 67 + 2];
        bb0 = b0[ch];
        float s1, q1;
        stats1_sum(stats1, ch, s1, q1);
        const float mn = s1 * INV_NTOT;
        const float vr = q1 * INV_NTOT - mn * mn;
        sc0 = g0[ch] * rsqrtf(vr + BN_EPS);
        sh0 = be0[ch] - mn * sc0;
        bb1 = b1[ch];
    }
    float sc1, sh1;
    {
        const float mn = stats2[ch] * INV_NTOT;
        const float vr = stats2[64 + ch] * INV_NTOT - mn * mn;
        sc1 = g1[ch] * rsqrtf(vr + BN_EPS);
        sh1 = be1[ch] - mn * sc1;
    }
    const float bb2 = b2[c2];
    float sc2 = 0.f, sh2 = 0.f;
    if (FINAL) {
        const float mn = stats3[c2] * INV_NTOT;
        const float vr = stats3[128 + c2] * INV_NTOT - mn * mn;
        sc2 = g2[c2] * rsqrtf(vr + BN_EPS);
        sh2 = be2[c2] - mn * sc2;
    }
    float sl = 0.f, sq = 0.f, mx = -FLT_MAX;
    __syncthreads();

    const int base = blockIdx.x * 256;
    for (int t = 0; t < 64; ++t) {
        const int p = base + t * 4 + pl;
        if (RECOMP) {
            const int i = idx[p];
            const int bm = p >> 5;
            const int b  = bm >> 10;
            if (ch < 3)
                dls[pl][ch] = xyz[(((size_t)(b << 12)) + i) * 3 + ch]
                            - new_xyz[(size_t)bm * 3 + ch];
            __syncthreads();
            const float z0 = z0_calc(P1[(((size_t)(b << 12)) + i) * 64 + ch], bb0,
                                     wx0, wx1, wx2, dls[pl][0], dls[pl][1], dls[pl][2]);
            inb1[pl][ch] = fmaxf(fmaf(z0, sc0, sh0), 0.f);
            __syncthreads();
            float z1 = bb1;
#pragma unroll
            for (int ic = 0; ic < 64; ++ic)
                z1 = fmaf(w1sm[ch * 65 + ic], inb1[pl][ic], z1);
            inb2[pl][ch] = fmaxf(fmaf(z1, sc1, sh1), 0.f);
        } else {
            const float z1 = __bfloat162float(Z2[(size_t)p * 64 + ch]);
            inb2[pl][ch] = fmaxf(fmaf(z1, sc1, sh1), 0.f);
        }
        __syncthreads();

#pragma unroll
        for (int q = 0; q < 2; ++q) {
            const int pr = q * 2 + p2;
            float z2 = bb2;
#pragma unroll
            for (int ic = 0; ic < 64; ++ic)
                z2 = fmaf(w2sm[c2 * 65 + ic], inb2[pr][ic], z2);
            if (FINAL) {
                mx = fmaxf(mx, fmaxf(fmaf(z2, sc2, sh2), 0.f));
            } else {
                sl += z2; sq += z2 * z2;
            }
        }
        if (FINAL && ((t & 7) == 7)) {
            pmax[p2][c2] = mx;
            __syncthreads();
            if (p2 == 0)
                poolbuf[t >> 3][c2] = fmaxf(pmax[0][c2], pmax[1][c2]);
            mx = -FLT_MAX;
        }
        __syncthreads();
    }

    if (FINAL) {
        const int b  = base >> 15;
        const int m0 = (base >> 5) & 1023;
#pragma unroll
        for (int r = 0; r < 4; ++r) {
            const int o   = r * 256 + tid;
            const int row = o >> 3;
            const int gg  = o & 7;
            outNP[((size_t)(b * 128 + row)) * 1024 + m0 + gg] = poolbuf[gg][row];
        }
    } else {
        red[tid] = sl; red[256 + tid] = sq;
        __syncthreads();
        if (tid < 128) {
            atomicAdd(&stats_out[tid],       red[tid] + red[128 + tid]);
            atomicAdd(&stats_out[128 + tid], red[256 + tid] + red[256 + 128 + tid]);
        }
    }
}

// ---------------------------------------------------------------------------
extern "C" void kernel_launch(void* const* d_in, const int* in_sizes, int n_in,
                              void* d_out, int out_size, void* d_ws, size_t ws_size,
                              hipStream_t stream) {
    const float* xyz    = (const float*)d_in[0];
    const float* points = (const float*)d_in[1];
    const float* w0  = (const float*)d_in[2];
    const float* b0  = (const float*)d_in[3];
    const float* g0  = (const float*)d_in[4];
    const float* be0 = (const float*)d_in[5];
    const float* w1  = (const float*)d_in[6];
    const float* b1  = (const float*)d_in[7];
    const float* g1  = (const float*)d_in[8];
    const float* be1 = (const float*)d_in[9];
    const float* w2  = (const float*)d_in[10];
    const float* b2  = (const float*)d_in[11];
    const float* g2  = (const float*)d_in[12];
    const float* be2 = (const float*)d_in[13];

    float* out        = (float*)d_out;
    float* new_xyz    = out;
    float* new_points = out + (size_t)BATCH * NPOINT * 3;

    // ws: idx 2MB | stats 32KB (32-rep stats1 + stats2 + stats3) | P1 16MB
    //     | Z3max 8MB | Z3min 8MB | Z2 64MB
    char* ws = (char*)d_ws;
    int*   idx   = (int*)ws;
    float* stats = (float*)(ws + (size_t)(2u << 20));
    float* stats1 = stats;                 // 32 replicas x (sum64 | sumsq64)
    float* stats2 = stats + S1REP * 128;   // 128
    float* stats3 = stats2 + 128;          // 256
    float* P1    = (float*)(ws + (size_t)(2u << 20) + 32768);
    const size_t offMM = (size_t)(2u << 20) + 32768 + (size_t)BATCH * NPTS * 64 * 4;
    float* Z3max = (float*)(ws + offMM);
    float* Z3min = Z3max + (size_t)BATCH * NPOINT * 128;
    const size_t offZ2 = offMM + (size_t)BATCH * NPOINT * 128 * 4 * 2;
    __hip_bfloat16* Z2 = (__hip_bfloat16*)(ws + offZ2);

    const bool tierA = ws_size >= offZ2 + (size_t)NTOT * 64 * 2;  // ~98 MB
    const bool tierB = ws_size >= offZ2;                          // ~34 MB

    init_stats_kernel<<<1, 512, 0, stream>>>(stats);
    p1_kernel<<<BATCH * NPTS / 256, 256, 0, stream>>>(points, w0, P1);
    fps_kernel<<<BATCH, 256, 0, stream>>>(xyz, new_xyz);
    knn_kernel<<<dim3(NPOINT, BATCH), 256, 0, stream>>>(xyz, new_xyz, P1,
                                                        w0, b0, idx, stats1);
    if (tierA) {
        conv1_kernel<true><<<NTOT / 256, 256, 0, stream>>>(
            xyz, new_xyz, idx, P1, w0, b0, stats1, g0, be0, w1, b1, Z2, stats2);
        conv2s_kernel<false><<<NTOT / 256, 256, 0, stream>>>(
            xyz, new_xyz, idx, P1, w0, b0, stats1, g0, be0, w1, b1, Z2,
            stats2, g1, be1, w2, b2, stats3, Z3max, Z3min);
        pool_mm_kernel<<<dim3(32, BATCH), 256, 0, stream>>>(
            Z3max, Z3min, stats3, g2, be2, new_points);
    } else if (tierB) {
        conv1_kernel<false><<<NTOT / 256, 256, 0, stream>>>(
            xyz, new_xyz, idx, P1, w0, b0, stats1, g0, be0, w1, b1, Z2, stats2);
        conv2s_kernel<true><<<NTOT / 256, 256, 0, stream>>>(
            xyz, new_xyz, idx, P1, w0, b0, stats1, g0, be0, w1, b1, Z2,
            stats2, g1, be1, w2, b2, stats3, Z3max, Z3min);
        pool_mm_kernel<<<dim3(32, BATCH), 256, 0, stream>>>(
            Z3max, Z3min, stats3, g2, be2, new_points);
    } else {
        conv1_kernel<false><<<NTOT / 256, 256, 0, stream>>>(
            xyz, new_xyz, idx, P1, w0, b0, stats1, g0, be0, w1, b1, Z2, stats2);
        conv2_kernel<true, false><<<NTOT / 256, 256, 0, stream>>>(
            xyz, new_xyz, idx, P1, w0, b0, stats1, g0, be0, w1, b1, Z2,
            stats2, g1, be1, w2, b2, stats3, g2, be2, stats3, new_points);
        conv2_kernel<true, true><<<NTOT / 256, 256, 0, stream>>>(
            xyz, new_xyz, idx, P1, w0, b0, stats1, g0, be0, w1, b1, Z2,
            stats2, g1, be1, w2, b2, stats3, g2, be2, stats3, new_points);
    }
}

// Round 12
// 1534.701 us; speedup vs baseline: 1.8353x; 1.1004x over previous
//
#include <hip/hip_runtime.h>
#include <hip/hip_bf16.h>
#include <float.h>

#define NPTS    4096
#define NPOINT  1024
#define NSAMPLE 32
#define BATCH   16
#define NTOT    (BATCH * NPOINT * NSAMPLE)   // 524288 gathered pairs
#define INV_NTOT (1.0f / 524288.0f)
#define BN_EPS  1e-5f
#define S1REP   32                            // stats1 atomic replicas

// ---------------------------------------------------------------------------
// DPP wave-64 reduction helpers (pure VALU — no LDS-pipe bpermute/swizzle).
// ---------------------------------------------------------------------------
template<int CTRL, int OLD>
__device__ __forceinline__ unsigned long long dpp_move_u64(unsigned long long v) {
    const int lo = __builtin_amdgcn_update_dpp(OLD, (int)(unsigned)v,        CTRL, 0xF, 0xF, false);
    const int hi = __builtin_amdgcn_update_dpp(OLD, (int)(unsigned)(v >> 32), CTRL, 0xF, 0xF, false);
    return ((unsigned long long)(unsigned)hi << 32) | (unsigned)lo;
}

__device__ __forceinline__ unsigned long long dpp_max64_to_lane63(unsigned long long v) {
    unsigned long long o;
    o = dpp_move_u64<0x111, 0>(v); v = o > v ? o : v;
    o = dpp_move_u64<0x112, 0>(v); v = o > v ? o : v;
    o = dpp_move_u64<0x114, 0>(v); v = o > v ? o : v;
    o = dpp_move_u64<0x118, 0>(v); v = o > v ? o : v;
    o = dpp_move_u64<0x142, 0>(v); v = o > v ? o : v;
    o = dpp_move_u64<0x143, 0>(v); v = o > v ? o : v;
    return v;
}

__device__ __forceinline__ unsigned long long dpp_min64_to_lane63(unsigned long long v) {
    unsigned long long o;
    o = dpp_move_u64<0x111, -1>(v); v = o < v ? o : v;
    o = dpp_move_u64<0x112, -1>(v); v = o < v ? o : v;
    o = dpp_move_u64<0x114, -1>(v); v = o < v ? o : v;
    o = dpp_move_u64<0x118, -1>(v); v = o < v ? o : v;
    o = dpp_move_u64<0x142, -1>(v); v = o < v ? o : v;
    o = dpp_move_u64<0x143, -1>(v); v = o < v ? o : v;
    return v;
}

__device__ __forceinline__ unsigned long long readlane63_u64(unsigned long long v) {
    const unsigned lo = (unsigned)__builtin_amdgcn_readlane((int)(unsigned)v, 63);
    const unsigned hi = (unsigned)__builtin_amdgcn_readlane((int)(unsigned)(v >> 32), 63);
    return ((unsigned long long)hi << 32) | lo;
}

// ---------------------------------------------------------------------------
__global__ void init_stats_kernel(float* __restrict__ stats) {
#pragma unroll
    for (int t = 0; t < 9; ++t)
        stats[t * 512 + threadIdx.x] = 0.0f;
}

// ---------------------------------------------------------------------------
// K1: FPS — round-11 version (620 µs, best measured). 256 thr, 16 pts/thread.
// ---------------------------------------------------------------------------
__global__ __launch_bounds__(256) void fps_kernel(const float* __restrict__ xyz,
                                                  float* __restrict__ new_xyz) {
#pragma clang fp contract(off)
    const int b = blockIdx.x, tid = threadIdx.x;
    const int lane = tid & 63, wave = tid >> 6;
    const float* X = xyz + (size_t)b * NPTS * 3;
    float* outC = new_xyz + (size_t)b * NPOINT * 3;

    __shared__ float xs[NPTS], ys[NPTS], zs[NPTS];
    __shared__ unsigned long long wred[2][4];

    float px[16], py[16], pz[16], dd[16];
    unsigned idneg[16];
#pragma unroll
    for (int k = 0; k < 16; ++k) {
        const int i = tid + k * 256;
        px[k] = X[i * 3 + 0]; py[k] = X[i * 3 + 1]; pz[k] = X[i * 3 + 2];
        dd[k] = 1e10f;
        idneg[k] = (unsigned)(4095 - i);
        xs[i] = px[k]; ys[i] = py[k]; zs[i] = pz[k];
    }
    __syncthreads();

    int far = 0;
    for (int it = 0; it < NPOINT; ++it) {
        const float cx = xs[far], cy = ys[far], cz = zs[far];
        if (tid == 0) {
            outC[it * 3 + 0] = cx; outC[it * 3 + 1] = cy; outC[it * 3 + 2] = cz;
        }
        float bv = -1.0f; unsigned biNeg = 0;
#pragma unroll
        for (int k = 0; k < 16; ++k) {
            const float dx = px[k] - cx, dy = py[k] - cy, dz = pz[k] - cz;
            const float dist = (dx * dx + dy * dy) + dz * dz;
            const float nd = fminf(dd[k], dist);
            dd[k] = nd;
            const bool gt = nd > bv;
            bv = gt ? nd : bv;
            biNeg = gt ? idneg[k] : biNeg;
        }
        unsigned long long best =
            ((unsigned long long)__float_as_uint(bv) << 32) | biNeg;
        best = dpp_max64_to_lane63(best);
        if (lane == 63) wred[it & 1][wave] = best;
        __syncthreads();
        unsigned long long g = wred[it & 1][0];
#pragma unroll
        for (int w = 1; w < 4; ++w) {
            const unsigned long long o = wred[it & 1][w];
            g = o > g ? o : g;
        }
        far = 4095 - (int)(g & 0xFFFFFFFFull);
    }
}

// ---------------------------------------------------------------------------
// K2: k-nearest + fused layer-0 stats (round-11 version, frozen).
// ---------------------------------------------------------------------------
__global__ __launch_bounds__(256) void knn_kernel(const float* __restrict__ xyz,
                                                  const float* __restrict__ new_xyz,
                                                  const float* __restrict__ P1,
                                                  const float* __restrict__ w0,
                                                  const float* __restrict__ b0,
                                                  int* __restrict__ idx,
                                                  float* __restrict__ stats1) {
#pragma clang fp contract(off)
    const int m = blockIdx.x, b = blockIdx.y;
    const int tid = threadIdx.x;
    const int lane = tid & 63, wave = tid >> 6;
    const float* X = xyz + (size_t)b * NPTS * 3;
    const float* c = new_xyz + ((size_t)b * NPOINT + m) * 3;
    const float cx = c[0], cy = c[1], cz = c[2];
    const float sqc = (cx * cx + cy * cy) + cz * cz;

    unsigned long long key[16];
#pragma unroll
    for (int k = 0; k < 16; ++k) {
        const int i = wave * 1024 + k * 64 + lane;
        const float x = X[i * 3 + 0];
        const float y = X[i * 3 + 1];
        const float z = X[i * 3 + 2];
        const float sqi = (x * x + y * y) + z * z;
        const float dot = (cx * x + cy * y) + cz * z;
        const float d2 = (sqc + sqi) - 2.0f * dot;
        const unsigned u = __float_as_uint(d2);
        const unsigned s = u ^ (unsigned)(((int)u >> 31) | 0x80000000);
        key[k] = ((unsigned long long)s << 32) | (unsigned)i;
    }

    __shared__ unsigned long long wk[128];
    __shared__ int widx[32];
    __shared__ float red[512];

    for (int j = 0; j < NSAMPLE; ++j) {
        unsigned long long best = key[0];
#pragma unroll
        for (int k = 1; k < 16; ++k) best = key[k] < best ? key[k] : best;
        best = dpp_min64_to_lane63(best);
        const unsigned long long bestAll = readlane63_u64(best);
        if (lane == 0) wk[wave * 32 + j] = bestAll;
#pragma unroll
        for (int k = 0; k < 16; ++k)
            key[k] = (key[k] == bestAll) ? ~0ull : key[k];
    }
    __syncthreads();

    if (wave == 0) {
        int* out = idx + ((size_t)b * NPOINT + m) * NSAMPLE;
        unsigned long long a = wk[lane], bb = wk[64 + lane];
        for (int j = 0; j < NSAMPLE; ++j) {
            unsigned long long best = a < bb ? a : bb;
            best = dpp_min64_to_lane63(best);
            const unsigned long long bestAll = readlane63_u64(best);
            if (lane == 0) {
                const int gi = (int)(bestAll & 0xFFFFFFFFull);
                out[j] = gi;
                widx[j] = gi;
            }
            a  = (a  == bestAll) ? ~0ull : a;
            bb = (bb == bestAll) ? ~0ull : bb;
        }
    }
    __syncthreads();

    const int ch = tid & 63, grp = tid >> 6;
    const float wx0 = w0[ch * 67 + 0], wx1 = w0[ch * 67 + 1], wx2 = w0[ch * 67 + 2];
    const float bb0 = b0[ch];
    float sl = 0.f, sq = 0.f;
#pragma unroll
    for (int j = 0; j < 8; ++j) {
        const int i = widx[grp * 8 + j];
        const float dx = X[i * 3 + 0] - cx;
        const float dy = X[i * 3 + 1] - cy;
        const float dz = X[i * 3 + 2] - cz;
        const float p1v = P1[(((size_t)(b << 12)) + i) * 64 + ch];
        const float z = fmaf(wx2, dz, fmaf(wx1, dy, fmaf(wx0, dx, p1v + bb0)));
        sl += z; sq += z * z;
    }
    red[tid] = sl; red[256 + tid] = sq;
    __syncthreads();
    if (grp == 0) {
        float* rep = stats1 + (size_t)(m & (S1REP - 1)) * 128;
        atomicAdd(&rep[ch],
                  red[ch] + red[64 + ch] + red[128 + ch] + red[192 + ch]);
        atomicAdd(&rep[64 + ch],
                  red[256 + ch] + red[256 + 64 + ch] + red[256 + 128 + ch] + red[256 + 192 + ch]);
    }
}

// ---------------------------------------------------------------------------
// K3: P1 = points @ w0[:,3:]^T — unchanged.
// ---------------------------------------------------------------------------
__global__ __launch_bounds__(256) void p1_kernel(const float* __restrict__ points,
                                                 const float* __restrict__ w0,
                                                 float* __restrict__ P1) {
    const int tid = threadIdx.x;
    const int ch = tid & 63, pg = tid >> 6;
    __shared__ float wld[64 * 65];
    __shared__ float inb[16][68];
    for (int t = tid; t < 64 * 64; t += 256)
        wld[(t >> 6) * 65 + (t & 63)] = w0[(t >> 6) * 67 + 3 + (t & 63)];
    __syncthreads();
    float wreg[64];
#pragma unroll
    for (int ic = 0; ic < 64; ++ic) wreg[ic] = wld[ch * 65 + ic];

    const int base = blockIdx.x * 256;
    for (int t = 0; t < 16; ++t) {
        const int q0 = base + t * 16;
#pragma unroll
        for (int k = 0; k < 4; ++k) {
            const int pos = pg + k * 4;
            inb[pos][ch] = points[(size_t)(q0 + pos) * 64 + ch];
        }
        __syncthreads();
#pragma unroll
        for (int j = 0; j < 4; ++j) {
            const int pos = pg * 4 + j;
            const float4* row = (const float4*)&inb[pos][0];
            float acc = 0.f;
#pragma unroll
            for (int ic4 = 0; ic4 < 16; ++ic4) {
                const float4 v = row[ic4];
                acc = fmaf(wreg[4 * ic4 + 0], v.x, acc);
                acc = fmaf(wreg[4 * ic4 + 1], v.y, acc);
                acc = fmaf(wreg[4 * ic4 + 2], v.z, acc);
                acc = fmaf(wreg[4 * ic4 + 3], v.w, acc);
            }
            P1[(size_t)(q0 + pos) * 64 + ch] = acc;
        }
        __syncthreads();
    }
}

__device__ __forceinline__ float z0_calc(float p1v, float bb, float wx0, float wx1,
                                         float wx2, float dx, float dy, float dz) {
    return fmaf(wx2, dz, fmaf(wx1, dy, fmaf(wx0, dx, p1v + bb)));
}

__device__ __forceinline__ void stats1_sum(const float* __restrict__ stats1,
                                           int ch, float& s, float& q) {
    s = 0.f; q = 0.f;
#pragma unroll
    for (int r = 0; r < S1REP; ++r) {
        s += stats1[r * 128 + ch];
        q += stats1[r * 128 + 64 + ch];
    }
}

// ---------------------------------------------------------------------------
// K5: conv1 — TWO channels per thread (chp, chp+32): each broadcast float4
// read feeds 8 FMAs (was 4) -> LDS-pipe traffic halved. Per-output FMA order
// unchanged -> bit-identical z1. Staging phase verbatim (chs = tid&63).
// ---------------------------------------------------------------------------
template<bool STORE>
__global__ __launch_bounds__(256) void conv1_kernel(
        const float* __restrict__ xyz, const float* __restrict__ new_xyz,
        const int* __restrict__ idx, const float* __restrict__ P1,
        const float* __restrict__ w0, const float* __restrict__ b0,
        const float* __restrict__ stats1,
        const float* __restrict__ g0, const float* __restrict__ be0,
        const float* __restrict__ w1, const float* __restrict__ b1,
        __hip_bfloat16* __restrict__ Z2, float* __restrict__ stats_out) {
    const int tid = threadIdx.x;
    const int chs = tid & 63, pgs = tid >> 6;   // staging layout
    const int chp = tid & 31, pg = tid >> 5;    // compute: channels chp, chp+32
    __shared__ float w1ld[64 * 65];
    __shared__ float inb1[16][68];
    __shared__ float dls[16][4];
    __shared__ int   iidx[16];
    __shared__ float red[1024];
    for (int t = tid; t < 64 * 64; t += 256)
        w1ld[(t >> 6) * 65 + (t & 63)] = w1[t];
    __syncthreads();
    float wr0[64], wr1[64];
#pragma unroll
    for (int ic = 0; ic < 64; ++ic) {
        wr0[ic] = w1ld[chp * 65 + ic];
        wr1[ic] = w1ld[(chp + 32) * 65 + ic];
    }

    const float wx0 = w0[chs * 67 + 0], wx1 = w0[chs * 67 + 1], wx2 = w0[chs * 67 + 2];
    const float bb0 = b0[chs];
    float s1, q1;
    stats1_sum(stats1, chs, s1, q1);
    const float mn = s1 * INV_NTOT;
    const float vr = q1 * INV_NTOT - mn * mn;
    const float sc0 = g0[chs] * rsqrtf(vr + BN_EPS);
    const float sh0 = be0[chs] - mn * sc0;
    const float bb1a = b1[chp], bb1b = b1[chp + 32];
    float sl0 = 0.f, sq0 = 0.f, sl1 = 0.f, sq1 = 0.f;

    const int base = blockIdx.x * 256;
    for (int t = 0; t < 16; ++t) {
        const int p0 = base + t * 16;
        if (tid < 48) {
            const int pos = tid / 3, c = tid - pos * 3;
            const int p = p0 + pos;
            const int bm = p >> 5, b = bm >> 10;
            const int i = idx[p];
            dls[pos][c] = xyz[(((size_t)(b << 12)) + i) * 3 + c]
                        - new_xyz[(size_t)bm * 3 + c];
        } else if (tid < 64) {
            iidx[tid - 48] = idx[p0 + tid - 48];
        }
        __syncthreads();
#pragma unroll
        for (int k = 0; k < 4; ++k) {
            const int pos = pgs + k * 4;
            const int p = p0 + pos;
            const int bm = p >> 5, b = bm >> 10;
            const int i = iidx[pos];
            const float z0 = z0_calc(P1[(((size_t)(b << 12)) + i) * 64 + chs], bb0,
                                     wx0, wx1, wx2, dls[pos][0], dls[pos][1], dls[pos][2]);
            inb1[pos][chs] = fmaxf(fmaf(z0, sc0, sh0), 0.f);
        }
        __syncthreads();
#pragma unroll
        for (int j = 0; j < 2; ++j) {
            const int pos = pg * 2 + j;
            const float4* row = (const float4*)&inb1[pos][0];
            float z1a = bb1a, z1b = bb1b;
#pragma unroll
            for (int ic4 = 0; ic4 < 16; ++ic4) {
                const float4 v = row[ic4];
                z1a = fmaf(wr0[4 * ic4 + 0], v.x, z1a);
                z1a = fmaf(wr0[4 * ic4 + 1], v.y, z1a);
                z1a = fmaf(wr0[4 * ic4 + 2], v.z, z1a);
                z1a = fmaf(wr0[4 * ic4 + 3], v.w, z1a);
                z1b = fmaf(wr1[4 * ic4 + 0], v.x, z1b);
                z1b = fmaf(wr1[4 * ic4 + 1], v.y, z1b);
                z1b = fmaf(wr1[4 * ic4 + 2], v.z, z1b);
                z1b = fmaf(wr1[4 * ic4 + 3], v.w, z1b);
            }
            if (STORE) {
                Z2[(size_t)(p0 + pos) * 64 + chp]      = __float2bfloat16(z1a);
                Z2[(size_t)(p0 + pos) * 64 + chp + 32] = __float2bfloat16(z1b);
            }
            sl0 += z1a; sq0 += z1a * z1a;
            sl1 += z1b; sq1 += z1b * z1b;
        }
        __syncthreads();
    }
    red[pg * 32 + chp]       = sl0;
    red[256 + pg * 32 + chp] = sq0;
    red[512 + pg * 32 + chp] = sl1;
    red[768 + pg * 32 + chp] = sq1;
    __syncthreads();
    if (tid < 64) {
        float s = 0.f, q = 0.f;
        if (tid < 32) {
#pragma unroll
            for (int g = 0; g < 8; ++g) {
                s += red[g * 32 + tid];
                q += red[256 + g * 32 + tid];
            }
        } else {
            const int c = tid - 32;
#pragma unroll
            for (int g = 0; g < 8; ++g) {
                s += red[512 + g * 32 + c];
                q += red[768 + g * 32 + c];
            }
        }
        atomicAdd(&stats_out[tid], s);
        atomicAdd(&stats_out[64 + tid], q);
    }
}

// ---------------------------------------------------------------------------
// K6: conv2 single pass — TWO channels per thread (cp, cp+64), 4 pos/thread
// per phase. LDS reads halved. stats3 + per-group z3 max/min as before.
// ---------------------------------------------------------------------------
template<bool RECOMP>
__global__ __launch_bounds__(256) void conv2s_kernel(
        const float* __restrict__ xyz, const float* __restrict__ new_xyz,
        const int* __restrict__ idx, const float* __restrict__ P1,
        const float* __restrict__ w0, const float* __restrict__ b0,
        const float* __restrict__ stats1,
        const float* __restrict__ g0, const float* __restrict__ be0,
        const float* __restrict__ w1, const float* __restrict__ b1,
        const __hip_bfloat16* __restrict__ Z2,
        const float* __restrict__ stats2,
        const float* __restrict__ g1, const float* __restrict__ be1,
        const float* __restrict__ w2, const float* __restrict__ b2,
        float* __restrict__ stats_out,
        float* __restrict__ Z3max, float* __restrict__ Z3min) {
    const int tid = threadIdx.x;
    const int ch = tid & 63, pg = tid >> 6;     // staging AND compute layout

    __shared__ float w2ld[128 * 65];
    __shared__ float w1sm[RECOMP ? 64 * 65 : 1];
    __shared__ float inb1[RECOMP ? 16 : 1][68];
    __shared__ float inb2[16][68];
    __shared__ float dls[RECOMP ? 16 : 1][4];
    __shared__ int   iidx[RECOMP ? 16 : 1];
    __shared__ float red[1024];
    __shared__ float pmax[4][128];
    __shared__ float pmin[4][128];

    for (int t = tid; t < 128 * 64; t += 256)
        w2ld[(t >> 6) * 65 + (t & 63)] = w2[t];
    if (RECOMP)
        for (int t = tid; t < 64 * 64; t += 256)
            w1sm[(t >> 6) * 65 + (t & 63)] = w1[t];
    __syncthreads();
    float wr0[64], wr1[64];
#pragma unroll
    for (int ic = 0; ic < 64; ++ic) {
        wr0[ic] = w2ld[ch * 65 + ic];
        wr1[ic] = w2ld[(ch + 64) * 65 + ic];
    }

    float wx0 = 0.f, wx1 = 0.f, wx2 = 0.f, bb0 = 0.f, sc0 = 0.f, sh0 = 0.f, bb1 = 0.f;
    if (RECOMP) {
        wx0 = w0[ch * 67 + 0]; wx1 = w0[ch * 67 + 1]; wx2 = w0[ch * 67 + 2];
        bb0 = b0[ch];
        float s1, q1;
        stats1_sum(stats1, ch, s1, q1);
        const float mn = s1 * INV_NTOT;
        const float vr = q1 * INV_NTOT - mn * mn;
        sc0 = g0[ch] * rsqrtf(vr + BN_EPS);
        sh0 = be0[ch] - mn * sc0;
        bb1 = b1[ch];
    }
    float sc1, sh1;
    {
        const float mn = stats2[ch] * INV_NTOT;
        const float vr = stats2[64 + ch] * INV_NTOT - mn * mn;
        sc1 = g1[ch] * rsqrtf(vr + BN_EPS);
        sh1 = be1[ch] - mn * sc1;
    }
    const float bb2a = b2[ch], bb2b = b2[ch + 64];
    float sl0 = 0.f, sq0 = 0.f, sl1 = 0.f, sq1 = 0.f;
    float mx0 = -FLT_MAX, mn0 = FLT_MAX, mx1 = -FLT_MAX, mn1 = FLT_MAX;

    const int base = blockIdx.x * 256;
    for (int t = 0; t < 16; ++t) {
        const int p0 = base + t * 16;
        if (RECOMP) {
            if (tid < 48) {
                const int pos = tid / 3, c = tid - pos * 3;
                const int p = p0 + pos;
                const int bm = p >> 5, b = bm >> 10;
                const int i = idx[p];
                dls[pos][c] = xyz[(((size_t)(b << 12)) + i) * 3 + c]
                            - new_xyz[(size_t)bm * 3 + c];
            } else if (tid < 64) {
                iidx[tid - 48] = idx[p0 + tid - 48];
            }
            __syncthreads();
#pragma unroll
            for (int k = 0; k < 4; ++k) {
                const int pos = pg + k * 4;
                const int p = p0 + pos;
                const int bm = p >> 5, b = bm >> 10;
                const int i = iidx[pos];
                const float z0 = z0_calc(P1[(((size_t)(b << 12)) + i) * 64 + ch], bb0,
                                         wx0, wx1, wx2, dls[pos][0], dls[pos][1], dls[pos][2]);
                inb1[pos][ch] = fmaxf(fmaf(z0, sc0, sh0), 0.f);
            }
            __syncthreads();
#pragma unroll
            for (int k = 0; k < 4; ++k) {
                const int pos = pg + k * 4;
                const float4* row1 = (const float4*)&inb1[pos][0];
                float z1 = bb1;
#pragma unroll
                for (int ic4 = 0; ic4 < 16; ++ic4) {
                    const float4 v = row1[ic4];
                    z1 = fmaf(w1sm[ch * 65 + 4 * ic4 + 0], v.x, z1);
                    z1 = fmaf(w1sm[ch * 65 + 4 * ic4 + 1], v.y, z1);
                    z1 = fmaf(w1sm[ch * 65 + 4 * ic4 + 2], v.z, z1);
                    z1 = fmaf(w1sm[ch * 65 + 4 * ic4 + 3], v.w, z1);
                }
                inb2[pos][ch] = fmaxf(fmaf(z1, sc1, sh1), 0.f);
            }
        } else {
#pragma unroll
            for (int k = 0; k < 4; ++k) {
                const int pos = pg + k * 4;
                const float z1 = __bfloat162float(Z2[(size_t)(p0 + pos) * 64 + ch]);
                inb2[pos][ch] = fmaxf(fmaf(z1, sc1, sh1), 0.f);
            }
        }
        __syncthreads();

#pragma unroll
        for (int j = 0; j < 4; ++j) {
            const int pos = pg * 4 + j;
            const float4* row2 = (const float4*)&inb2[pos][0];
            float z2a = bb2a, z2b = bb2b;
#pragma unroll
            for (int ic4 = 0; ic4 < 16; ++ic4) {
                const float4 v = row2[ic4];
                z2a = fmaf(wr0[4 * ic4 + 0], v.x, z2a);
                z2a = fmaf(wr0[4 * ic4 + 1], v.y, z2a);
                z2a = fmaf(wr0[4 * ic4 + 2], v.z, z2a);
                z2a = fmaf(wr0[4 * ic4 + 3], v.w, z2a);
                z2b = fmaf(wr1[4 * ic4 + 0], v.x, z2b);
                z2b = fmaf(wr1[4 * ic4 + 1], v.y, z2b);
                z2b = fmaf(wr1[4 * ic4 + 2], v.z, z2b);
                z2b = fmaf(wr1[4 * ic4 + 3], v.w, z2b);
            }
            sl0 += z2a; sq0 += z2a * z2a;
            sl1 += z2b; sq1 += z2b * z2b;
            mx0 = fmaxf(mx0, z2a); mn0 = fminf(mn0, z2a);
            mx1 = fmaxf(mx1, z2b); mn1 = fminf(mn1, z2b);
        }
        if (t & 1) {                        // 32-sample group complete
            pmax[pg][ch] = mx0; pmax[pg][64 + ch] = mx1;
            pmin[pg][ch] = mn0; pmin[pg][64 + ch] = mn1;
            __syncthreads();
            if (pg == 0) {
                const int bm = (base >> 5) + (t >> 1);
                const float ma = fmaxf(fmaxf(pmax[0][ch], pmax[1][ch]),
                                       fmaxf(pmax[2][ch], pmax[3][ch]));
                const float mb = fmaxf(fmaxf(pmax[0][64 + ch], pmax[1][64 + ch]),
                                       fmaxf(pmax[2][64 + ch], pmax[3][64 + ch]));
                const float na = fminf(fminf(pmin[0][ch], pmin[1][ch]),
                                       fminf(pmin[2][ch], pmin[3][ch]));
                const float nb = fminf(fminf(pmin[0][64 + ch], pmin[1][64 + ch]),
                                       fminf(pmin[2][64 + ch], pmin[3][64 + ch]));
                Z3max[(size_t)bm * 128 + ch]      = ma;
                Z3max[(size_t)bm * 128 + 64 + ch] = mb;
                Z3min[(size_t)bm * 128 + ch]      = na;
                Z3min[(size_t)bm * 128 + 64 + ch] = nb;
            }
            mx0 = -FLT_MAX; mn0 = FLT_MAX; mx1 = -FLT_MAX; mn1 = FLT_MAX;
        }
        __syncthreads();
    }

    red[pg * 64 + ch]       = sl0;
    red[256 + pg * 64 + ch] = sq0;
    red[512 + pg * 64 + ch] = sl1;
    red[768 + pg * 64 + ch] = sq1;
    __syncthreads();
    if (tid < 128) {
        float s = 0.f, q = 0.f;
        if (tid < 64) {
#pragma unroll
            for (int g = 0; g < 4; ++g) {
                s += red[g * 64 + tid];
                q += red[256 + g * 64 + tid];
            }
        } else {
            const int c = tid - 64;
#pragma unroll
            for (int g = 0; g < 4; ++g) {
                s += red[512 + g * 64 + c];
                q += red[768 + g * 64 + c];
            }
        }
        atomicAdd(&stats_out[tid], s);
        atomicAdd(&stats_out[128 + tid], q);
    }
}

// ---------------------------------------------------------------------------
// K7: epilogue — BN2+ReLU on the selected z3 extreme, transposed write.
// ---------------------------------------------------------------------------
__global__ __launch_bounds__(256) void pool_mm_kernel(
        const float* __restrict__ Z3max, const float* __restrict__ Z3min,
        const float* __restrict__ stats,
        const float* __restrict__ g, const float* __restrict__ beta,
        float* __restrict__ outNP) {
    const int tid = threadIdx.x;
    const int mtile = blockIdx.x;    // 0..31
    const int b = blockIdx.y;        // 0..15
    const int ch = tid & 127, mh = tid >> 7;

    const float mean  = stats[ch] * INV_NTOT;
    const float var   = stats[128 + ch] * INV_NTOT - mean * mean;
    const float scale = g[ch] * rsqrtf(var + BN_EPS);
    const float shift = beta[ch] - mean * scale;

    __shared__ float pool[32][129];

    for (int pass = 0; pass < 16; ++pass) {
        const int ml = pass * 2 + mh;
        const size_t bm = (size_t)b * NPOINT + mtile * 32 + ml;
        const float zx = Z3max[bm * 128 + ch];
        const float zn = Z3min[bm * 128 + ch];
        const float zsel = (scale >= 0.f) ? zx : zn;
        pool[ml][ch] = fmaxf(fmaf(zsel, scale, shift), 0.f);
    }
    __syncthreads();

#pragma unroll
    for (int r = 0; r < 16; ++r) {
        const int o  = r * 256 + tid;
        const int ml = o & 31;
        const int c2 = o >> 5;
        outNP[((size_t)b * 128 + c2) * NPOINT + mtile * 32 + ml] = pool[ml][c2];
    }
}

// ---------------------------------------------------------------------------
// Legacy tier-C fallback (conv2 double pass) — stats1 via replica sum.
// ---------------------------------------------------------------------------
template<bool RECOMP, bool FINAL>
__global__ __launch_bounds__(256) void conv2_kernel(
        const float* __restrict__ xyz, const float* __restrict__ new_xyz,
        const int* __restrict__ idx, const float* __restrict__ P1,
        const float* __restrict__ w0, const float* __restrict__ b0,
        const float* __restrict__ stats1,
        const float* __restrict__ g0, const float* __restrict__ be0,
        const float* __restrict__ w1, const float* __restrict__ b1,
        const __hip_bfloat16* __restrict__ Z2,
        const float* __restrict__ stats2,
        const float* __restrict__ g1, const float* __restrict__ be1,
        const float* __restrict__ w2, const float* __restrict__ b2,
        const float* __restrict__ stats3,
        const float* __restrict__ g2, const float* __restrict__ be2,
        float* __restrict__ stats_out, float* __restrict__ outNP) {
    const int tid = threadIdx.x;
    const int ch = tid & 63,  pl = tid >> 6;
    const int c2 = tid & 127, p2 = tid >> 7;

    __shared__ float w2sm[128 * 65];
    __shared__ float w1sm[RECOMP ? 64 * 65 : 1];
    __shared__ float inb1[RECOMP ? 4 : 1][65];
    __shared__ float inb2[4][65];
    __shared__ float dls[4][4];
    __shared__ float red[FINAL ? 1 : 512];
    __shared__ float pmax[FINAL ? 2 : 1][128];
    __shared__ float poolbuf[FINAL ? 8 : 1][129];

    for (int t = tid; t < 128 * 64; t += 256)
        w2sm[(t >> 6) * 65 + (t & 63)] = w2[t];
    if (RECOMP)
        for (int t = tid; t < 64 * 64; t += 256)
            w1sm[(t >> 6) * 65 + (t & 63)] = w1[t];

    float wx0 = 0.f, wx1 = 0.f, wx2 = 0.f, bb0 = 0.f, sc0 = 0.f, sh0 = 0.f, bb1 = 0.f;
    if (RECOMP) {
        wx0 = w0[ch * 67 + 0]; wx1 = w0[ch * 67 + 1]; wx2 = w0[ch * 67 + 2];
        bb0 = b0[ch];
        float s1, q1;
        stats1_sum(stats1, ch, s1, q1);
        const float mn = s1 * INV_NTOT;
        const float vr = q1 * INV_NTOT - mn * mn;
        sc0 = g0[ch] * rsqrtf(vr + BN_EPS);
        sh0 = be0[ch] - mn * sc0;
        bb1 = b1[ch];
    }
    float sc1, sh1;
    {
        const float mn = stats2[ch] * INV_NTOT;
        const float vr = stats2[64 + ch] * INV_NTOT - mn * mn;
        sc1 = g1[ch] * rsqrtf(vr + BN_EPS);
        sh1 = be1[ch] - mn * sc1;
    }
    const float bb2 = b2[c2];
    float sc2 = 0.f, sh2 = 0.f;
    if (FINAL) {
        const float mn = stats3[c2] * INV_NTOT;
        const float vr = stats3[128 + c2] * INV_NTOT - mn * mn;
        sc2 = g2[c2] * rsqrtf(vr + BN_EPS);
        sh2 = be2[c2] - mn * sc2;
    }
    float sl = 0.f, sq = 0.f, mx = -FLT_MAX;
    __syncthreads();

    const int base = blockIdx.x * 256;
    for (int t = 0; t < 64; ++t) {
        const int p = base + t * 4 + pl;
        if (RECOMP) {
            const int i = idx[p];
            const int bm = p >> 5;
            const int b  = bm >> 10;
            if (ch < 3)
                dls[pl][ch] = xyz[(((size_t)(b << 12)) + i) * 3 + ch]
                            - new_xyz[(size_t)bm * 3 + ch];
            __syncthreads();
            const float z0 = z0_calc(P1[(((size_t)(b << 12)) + i) * 64 + ch], bb0,
                                     wx0, wx1, wx2, dls[pl][0], dls[pl][1], dls[pl][2]);
            inb1[pl][ch] = fmaxf(fmaf(z0, sc0, sh0), 0.f);
            __syncthreads();
            float z1 = bb1;
#pragma unroll
            for (int ic = 0; ic < 64; ++ic)
                z1 = fmaf(w1sm[ch * 65 + ic], inb1[pl][ic], z1);
            inb2[pl][ch] = fmaxf(fmaf(z1, sc1, sh1), 0.f);
        } else {
            const float z1 = __bfloat162float(Z2[(size_t)p * 64 + ch]);
            inb2[pl][ch] = fmaxf(fmaf(z1, sc1, sh1), 0.f);
        }
        __syncthreads();

#pragma unroll
        for (int q = 0; q < 2; ++q) {
            const int pr = q * 2 + p2;
            float z2 = bb2;
#pragma unroll
            for (int ic = 0; ic < 64; ++ic)
                z2 = fmaf(w2sm[c2 * 65 + ic], inb2[pr][ic], z2);
            if (FINAL) {
                mx = fmaxf(mx, fmaxf(fmaf(z2, sc2, sh2), 0.f));
            } else {
                sl += z2; sq += z2 * z2;
            }
        }
        if (FINAL && ((t & 7) == 7)) {
            pmax[p2][c2] = mx;
            __syncthreads();
            if (p2 == 0)
                poolbuf[t >> 3][c2] = fmaxf(pmax[0][c2], pmax[1][c2]);
            mx = -FLT_MAX;
        }
        __syncthreads();
    }

    if (FINAL) {
        const int b  = base >> 15;
        const int m0 = (base >> 5) & 1023;
#pragma unroll
        for (int r = 0; r < 4; ++r) {
            const int o   = r * 256 + tid;
            const int row = o >> 3;
            const int gg  = o & 7;
            outNP[((size_t)(b * 128 + row)) * 1024 + m0 + gg] = poolbuf[gg][row];
        }
    } else {
        red[tid] = sl; red[256 + tid] = sq;
        __syncthreads();
        if (tid < 128) {
            atomicAdd(&stats_out[tid],       red[tid] + red[128 + tid]);
            atomicAdd(&stats_out[128 + tid], red[256 + tid] + red[256 + 128 + tid]);
        }
    }
}

// ---------------------------------------------------------------------------
extern "C" void kernel_launch(void* const* d_in, const int* in_sizes, int n_in,
                              void* d_out, int out_size, void* d_ws, size_t ws_size,
                              hipStream_t stream) {
    const float* xyz    = (const float*)d_in[0];
    const float* points = (const float*)d_in[1];
    const float* w0  = (const float*)d_in[2];
    const float* b0  = (const float*)d_in[3];
    const float* g0  = (const float*)d_in[4];
    const float* be0 = (const float*)d_in[5];
    const float* w1  = (const float*)d_in[6];
    const float* b1  = (const float*)d_in[7];
    const float* g1  = (const float*)d_in[8];
    const float* be1 = (const float*)d_in[9];
    const float* w2  = (const float*)d_in[10];
    const float* b2  = (const float*)d_in[11];
    const float* g2  = (const float*)d_in[12];
    const float* be2 = (const float*)d_in[13];

    float* out        = (float*)d_out;
    float* new_xyz    = out;
    float* new_points = out + (size_t)BATCH * NPOINT * 3;

    // ws: idx 2MB | stats 32KB (32-rep stats1 + stats2 + stats3) | P1 16MB
    //     | Z3max 8MB | Z3min 8MB | Z2 64MB
    char* ws = (char*)d_ws;
    int*   idx   = (int*)ws;
    float* stats = (float*)(ws + (size_t)(2u << 20));
    float* stats1 = stats;                 // 32 replicas x (sum64 | sumsq64)
    float* stats2 = stats + S1REP * 128;   // 128
    float* stats3 = stats2 + 128;          // 256
    float* P1    = (float*)(ws + (size_t)(2u << 20) + 32768);
    const size_t offMM = (size_t)(2u << 20) + 32768 + (size_t)BATCH * NPTS * 64 * 4;
    float* Z3max = (float*)(ws + offMM);
    float* Z3min = Z3max + (size_t)BATCH * NPOINT * 128;
    const size_t offZ2 = offMM + (size_t)BATCH * NPOINT * 128 * 4 * 2;
    __hip_bfloat16* Z2 = (__hip_bfloat16*)(ws + offZ2);

    const bool tierA = ws_size >= offZ2 + (size_t)NTOT * 64 * 2;  // ~98 MB
    const bool tierB = ws_size >= offZ2;                          // ~34 MB

    init_stats_kernel<<<1, 512, 0, stream>>>(stats);
    p1_kernel<<<BATCH * NPTS / 256, 256, 0, stream>>>(points, w0, P1);
    fps_kernel<<<BATCH, 256, 0, stream>>>(xyz, new_xyz);
    knn_kernel<<<dim3(NPOINT, BATCH), 256, 0, stream>>>(xyz, new_xyz, P1,
                                                        w0, b0, idx, stats1);
    if (tierA) {
        conv1_kernel<true><<<NTOT / 256, 256, 0, stream>>>(
            xyz, new_xyz, idx, P1, w0, b0, stats1, g0, be0, w1, b1, Z2, stats2);
        conv2s_kernel<false><<<NTOT / 256, 256, 0, stream>>>(
            xyz, new_xyz, idx, P1, w0, b0, stats1, g0, be0, w1, b1, Z2,
            stats2, g1, be1, w2, b2, stats3, Z3max, Z3min);
        pool_mm_kernel<<<dim3(32, BATCH), 256, 0, stream>>>(
            Z3max, Z3min, stats3, g2, be2, new_points);
    } else if (tierB) {
        conv1_kernel<false><<<NTOT / 256, 256, 0, stream>>>(
            xyz, new_xyz, idx, P1, w0, b0, stats1, g0, be0, w1, b1, Z2, stats2);
        conv2s_kernel<true><<<NTOT / 256, 256, 0, stream>>>(
            xyz, new_xyz, idx, P1, w0, b0, stats1, g0, be0, w1, b1, Z2,
            stats2, g1, be1, w2, b2, stats3, Z3max, Z3min);
        pool_mm_kernel<<<dim3(32, BATCH), 256, 0, stream>>>(
            Z3max, Z3min, stats3, g2, be2, new_points);
    } else {
        conv1_kernel<false><<<NTOT / 256, 256, 0, stream>>>(
            xyz, new_xyz, idx, P1, w0, b0, stats1, g0, be0, w1, b1, Z2, stats2);
        conv2_kernel<true, false><<<NTOT / 256, 256, 0, stream>>>(
            xyz, new_xyz, idx, P1, w0, b0, stats1, g0, be0, w1, b1, Z2,
            stats2, g1, be1, w2, b2, stats3, g2, be2, stats3, new_points);
        conv2_kernel<true, true><<<NTOT / 256, 256, 0, stream>>>(
            xyz, new_xyz, idx, P1, w0, b0, stats1, g0, be0, w1, b1, Z2,
            stats2, g1, be1, w2, b2, stats3, g2, be2, stats3, new_points);
    }
}